// Round 17
// baseline (190.302 us; speedup 1.0000x reference)
//
#include <hip/hip_runtime.h>
#include <hip/hip_fp16.h>

#define N_NODES 100000
#define N_EDGES 1600000
#define D_IN 30
#define H_HEADS 4
#define C_OUT 30
#define EPSV 1e-5f
#define NEG 0.2f
#define MAXDEG 48
#define NPB 64
#define NBUCK 512             // bucket == build granule (196 nodes)
#define BUCK_NODES 196
#define BUILD_BLOCKS 511      // ceil(N/196)
#define SLICE_CAP 24          // mean 8 (4096 edges/512 buckets), P(>24) ~ e^-34
#define EPB 4096
#define BIN_BLOCKS ((N_EDGES + EPB - 1) / EPB)   // 391 (512-thread blocks)
#define STATS_BLOCKS 224
#define X_BLOCKS ((N_NODES + NPB - 1) / NPB)     // 1563
#define NODE_BLOCKS (N_NODES / 16)               // 6250

// ws layout (float offsets) — total 21,614,240 floats = 86.5 MB (< proven 92)
#define OFF_XH    0            // N*64 u32: 4 heads x {15 fp16x2, fp32 asrc} 256B rows
#define OFF_ADST  6400000      // N*4
#define OFF_PAR   6800000      // 4096
#define OFF_DEG   6804096      // N ints (+pad)
#define OFF_STATS 6904256      // 64
#define OFF_BCNTG 6904320      // BIN_BLOCKS*512 u32 = 200,192 (+pad)
#define OFF_ADJ   7105024      // N*MAXDEG u32
#define OFF_GBUF  11905024     // NBUCK*BIN_BLOCKS*SLICE_CAP uint2 = 9,609,216
#define OFF_PERM  21514240     // N ints (degree-sorted node permutation)

__device__ __forceinline__ float hb2f(unsigned int bits) {
    __half_raw r; r.x = (unsigned short)bits;
    return __half2float(*reinterpret_cast<__half*>(&r));
}

// 512-thread blocks. [0, BIN_BLOCKS): bin 4096 edges into block-PRIVATE slices
// keyed on d/196 (bucket == build granule) AND accumulate the edge-weight sum
// (stats blocks no longer re-read ew). Remaining STATS_BLOCKS: BN stats on h.
__global__ __launch_bounds__(512) void k_bin(const int* __restrict__ ei,
                                             const float* __restrict__ ew,
                                             const float* __restrict__ h,
                                             unsigned int* __restrict__ bcnt_g,
                                             uint2* __restrict__ gbuf,
                                             float* __restrict__ stats) {
    int t = threadIdx.x;
    if (blockIdx.x < BIN_BLOCKS) {
        __shared__ int bcnt[NBUCK];
        bcnt[t] = 0;                         // blockDim == NBUCK == 512
        __syncthreads();
        int blk = blockIdx.x;
        int j0 = blk * EPB + t;
        float es = 0.f;
#pragma unroll
        for (int r = 0; r < 8; ++r) {
            int j = j0 + r * 512;
            if (j < N_EDGES) {
                int s = __builtin_nontemporal_load(ei + j);
                int d = __builtin_nontemporal_load(ei + N_EDGES + j);
                float w = __builtin_nontemporal_load(ew + j);
                es += w;
                __half hv = __float2half_rn(w);
                unsigned short hb = *reinterpret_cast<unsigned short*>(&hv);
                unsigned lo = ((unsigned)s << 15) | (unsigned)(hb & 0x7FFFu);
                int b = d / BUCK_NODES;
                int rank = atomicAdd(&bcnt[b], 1);
                if (rank < SLICE_CAP)
                    gbuf[((size_t)b * BIN_BLOCKS + blk) * SLICE_CAP + rank] =
                        make_uint2(lo, (unsigned)d);
            }
        }
        for (int off = 32; off; off >>= 1) es += __shfl_down(es, off);
        if ((t & 63) == 0) atomicAdd(&stats[60], es);
        __syncthreads();
        bcnt_g[(size_t)blk * NBUCK + t] = (unsigned)bcnt[t];   // coalesced
        return;
    }
    __shared__ float ls[60];
    if (t < 60) ls[t] = 0.f;
    __syncthreads();
    float s[D_IN], q[D_IN];
#pragma unroll
    for (int d = 0; d < D_IN; ++d) { s[d] = 0.f; q[d] = 0.f; }
    int idx0 = (blockIdx.x - BIN_BLOCKS) * 512 + t;
    int stride = STATS_BLOCKS * 512;
    for (int r = idx0; r < N_NODES; r += stride) {
        const float* row = h + r * D_IN;
#pragma unroll
        for (int d = 0; d < D_IN; ++d) { float v = row[d]; s[d] += v; q[d] += v * v; }
    }
#pragma unroll
    for (int d = 0; d < D_IN; ++d) {
        for (int off = 32; off; off >>= 1) {
            s[d] += __shfl_down(s[d], off);
            q[d] += __shfl_down(q[d], off);
        }
    }
    if ((t & 63) == 0) {
#pragma unroll
        for (int d = 0; d < D_IN; ++d) { atomicAdd(&ls[d], s[d]); atomicAdd(&ls[30 + d], q[d]); }
    }
    __syncthreads();
    if (t < 60) atomicAdd(&stats[t], ls[t]);
}

// blocks [0, BUILD_BLOCKS): build ONE bucket's (196 nodes) adjacency rows in
// LDS from its contiguous slice region — every record read exactly once.
// Emits degree-DESCENDING perm. Remaining X_BLOCKS: x rows + inline param fold.
__global__ __launch_bounds__(256) void k_bx(const unsigned int* __restrict__ bcnt_g,
                                            const uint2* __restrict__ gbuf,
                                            unsigned int* __restrict__ adj,
                                            int* __restrict__ deg,
                                            int* __restrict__ perm,
                                            const float* __restrict__ h,
                                            const float* __restrict__ W,
                                            const float* __restrict__ Wedge,
                                            const float* __restrict__ att_edge,
                                            const float* __restrict__ att_src,
                                            const float* __restrict__ att_dst,
                                            const float* __restrict__ gamma,
                                            const float* __restrict__ beta,
                                            const float* __restrict__ stats,
                                            float* __restrict__ par,
                                            unsigned int* __restrict__ xh,
                                            float* __restrict__ adst) {
    __shared__ __align__(16) unsigned char smem[38816];
    int t = threadIdx.x;
    if (blockIdx.x < BUILD_BLOCKS) {
        unsigned* rows = (unsigned*)smem;              // [196*MAXDEG]
        int* cnt = (int*)(smem + 37632);               // [196]
        int* hist = (int*)(smem + 38416);              // [49]
        int* pfx  = (int*)(smem + 38612);              // [49]
        int b = blockIdx.x;
        int lo = b * BUCK_NODES;
        int lim = N_NODES - lo; if (lim > BUCK_NODES) lim = BUCK_NODES;
        for (int i = t; i < BUCK_NODES; i += 256) cnt[i] = 0;
        if (t < 49) hist[t] = 0;
        __syncthreads();
        const uint2* brec = gbuf + (size_t)b * BIN_BLOCKS * SLICE_CAP;
        int totslots = BIN_BLOCKS * SLICE_CAP;         // 9384
        for (int i = t; i < totslots; i += 256) {
            int sl = i / SLICE_CAP;
            int r = i - sl * SLICE_CAP;
            unsigned c = bcnt_g[(size_t)sl * NBUCK + b];
            if (r < (int)c) {                          // r < 24 always; c may exceed cap
                uint2 rec = brec[i];
                int li = (int)rec.y - lo;              // always in [0, lim) by keying
                int p = atomicAdd(&cnt[li], 1);
                if (p < MAXDEG) rows[li * MAXDEG + p] = rec.x;
            }
        }
        __syncthreads();
        int tot = lim * MAXDEG;
        for (int i = t; i < tot; i += 256) {
            int li = i / MAXDEG;
            int p = i - li * MAXDEG;
            if (p < cnt[li]) adj[(size_t)lo * MAXDEG + i] = rows[i];
        }
        for (int i = t; i < lim; i += 256) {
            int c = cnt[i]; c = (c > MAXDEG) ? MAXDEG : c;
            deg[lo + i] = c;
            atomicAdd(&hist[c], 1);
        }
        __syncthreads();
        if (t == 0) {                       // descending prefix (high-deg first)
            int acc = 0;
            for (int kk = MAXDEG; kk >= 0; --kk) { pfx[kk] = acc; acc += hist[kk]; }
        }
        __syncthreads();
        for (int i = t; i < lim; i += 256) {
            int c = cnt[i]; c = (c > MAXDEG) ? MAXDEG : c;
            int r = atomicAdd(&pfx[c], 1);
            perm[lo + r] = lo + i;
        }
        return;
    }
    float* W2s = (float*)smem;                 // 3600
    float* hs  = (float*)(smem + 14400);       // 1920
    float* psd = (float*)(smem + 22080);       // 240
    float* cq  = (float*)(smem + 23040);       // 8
    float* b2s = (float*)(smem + 23072);       // 120
    float* scs = (float*)(smem + 23552);       // 30
    float* shs = (float*)(smem + 23672);       // 30
    int bx = blockIdx.x - BUILD_BLOCKS;
    if (t < D_IN) {
        float mu = stats[t] * (1.f / N_NODES);
        float var = stats[30 + t] * (1.f / N_NODES) - mu * mu;
        float inv = 1.f / sqrtf(var + EPSV);
        float sc = gamma[t] * inv;
        scs[t] = sc; shs[t] = beta[t] - mu * sc;
    }
    __syncthreads();
    {   // vectorized: 900 float4; 4|120 so scs index constant per float4
        const float4* W4 = (const float4*)W;
        for (int i = t; i < 900; i += 256) {
            float4 w4 = W4[i];
            float sc = scs[(i * 4) / 120];
            w4.x *= sc; w4.y *= sc; w4.z *= sc; w4.w *= sc;
            *(float4*)&W2s[i * 4] = w4;
        }
    }
    if (t >= 128 && t < 248) {
        int c = t - 128;
        float b = 0.f;
#pragma unroll
        for (int d = 0; d < D_IN; ++d) b = fmaf(shs[d], W[d * 120 + c], b);
        b2s[c] = b;
    }
    if (bx == 0 && t >= 248 && t < 252) {
        int hh = t - 248;
        float k = 0.f;
        for (int c = 0; c < 30; ++c) k = fmaf(Wedge[hh * 30 + c], att_edge[hh * 30 + c], k);
        par[64 + hh] = k;
    }
    if (bx == 0 && t == 252) par[68] = stats[60] * (1.f / N_EDGES);
    __syncthreads();
    int base = bx * NPB;
    int cnt2 = N_NODES - base; if (cnt2 > NPB) cnt2 = NPB;
    if (t < 240) {
        int d = t >> 3, q = t & 7, hh = q & 3;
        const float* att = (q < 4) ? att_src : att_dst;
        float sum = 0.f;
#pragma unroll
        for (int c = 0; c < 30; ++c) sum = fmaf(W2s[d * 120 + hh * 30 + c], att[hh * 30 + c], sum);
        psd[t] = sum;
    }
    if (t >= 240 && t < 248) {
        int q = t - 240, hh = q & 3;
        const float* att = (q < 4) ? att_src : att_dst;
        float sum = 0.f;
#pragma unroll
        for (int c = 0; c < 30; ++c) sum = fmaf(b2s[hh * 30 + c], att[hh * 30 + c], sum);
        cq[q] = sum;
    }
    {   // vectorized h staging
        const float4* h4 = (const float4*)(h + (size_t)base * 30);
        int n4 = (cnt2 * 30) >> 2;
        for (int i = t; i < n4; i += 256) ((float4*)hs)[i] = h4[i];
    }
    __syncthreads();
    const float2* W2p = (const float2*)W2s;
    int total = cnt2 * 60;
    for (int o = t; o < total; o += 256) {
        int node = o / 60, p = o - node * 60;
        const float* hrow = hs + node * 30;
        float ax = b2s[2 * p], ay = b2s[2 * p + 1];
        const float2* Wp = W2p + p;
#pragma unroll
        for (int d = 0; d < 30; ++d) {
            float hv = hrow[d];
            float2 w = Wp[d * 60];
            ax = fmaf(hv, w.x, ax);
            ay = fmaf(hv, w.y, ay);
        }
        __half2 pk = __float22half2_rn(make_float2(ax, ay));
        int hh = p / 15, j = p - hh * 15;
        xh[(size_t)(base + node) * 64 + hh * 16 + j] = *reinterpret_cast<unsigned int*>(&pk);
    }
    for (int v = t; v < cnt2 * 8; v += 256) {
        int node = v >> 3, q = v & 7;
        const float* hrow = hs + node * 30;
        float sum = cq[q];
#pragma unroll
        for (int d = 0; d < 30; ++d) sum = fmaf(hrow[d], psd[d * 8 + q], sum);
        int n = base + node;
        if (q < 4) xh[(size_t)n * 64 + q * 16 + 15] = __float_as_uint(sum);
        else       adst[n * H_HEADS + (q - 4)] = sum;
    }
}

// Software-pipelined issue/consume of 4-edge batches (A/B sets, 8 gathers in
// flight). Decision rule: if VGPR > 64 and this regresses, revert to R16 loop.
#define GISSUE(U0, ED, RR) {                                                    \
    unsigned ss_[4];                                                            \
    _Pragma("unroll")                                                           \
    for (int v = 0; v < 4; ++v) {                                               \
        int u = (U0) + v;                                                       \
        unsigned aw = (u < 16) ? aw0 : ((u < 32) ? aw1 : aw2);                  \
        ED[v] = (unsigned)__builtin_amdgcn_ds_bpermute(pb4 + ((u & 15) << 2), (int)aw); \
        ss_[v] = (u < dn) ? (ED[v] >> 15) : (unsigned)n;                        \
    }                                                                           \
    _Pragma("unroll")                                                           \
    for (int v = 0; v < 4; ++v) RR[v] = xh4[(size_t)ss_[v] * 16u + (unsigned)k]; \
}

#define GCONSUME(U0, ED, RR) {                                                  \
    _Pragma("unroll")                                                           \
    for (int v = 0; v < 4; ++v) {                                               \
        int u = (U0) + v;                                                       \
        bool valid = (u < dn);                                                  \
        float w = hb2f(ED[v] & 0x7FFFu);                                        \
        float as_ = __uint_as_float((unsigned)__builtin_amdgcn_ds_bpermute(asl_b, (int)RR[v].w)); \
        float zz = fmaf(w, kh, adn) + as_;                                      \
        zz = fmaxf(zz, NEG * zz);                                               \
        float ee = valid ? __expf(zz) : 0.f;                                    \
        den += ee;                                                              \
        float2 y0 = __half22float2(*(const __half2*)&RR[v].x);                  \
        float2 y1 = __half22float2(*(const __half2*)&RR[v].y);                  \
        float2 y2 = __half22float2(*(const __half2*)&RR[v].z);                  \
        float2 y3 = __half22float2(*(const __half2*)&RR[v].w);                  \
        a0.x = fmaf(ee, y0.x, a0.x); a0.y = fmaf(ee, y0.y, a0.y);               \
        a1.x = fmaf(ee, y1.x, a1.x); a1.y = fmaf(ee, y1.y, a1.y);               \
        a2.x = fmaf(ee, y2.x, a2.x); a2.y = fmaf(ee, y2.y, a2.y);               \
        a3.x = fmaf(ee, y3.x, a3.x); a3.y = fmaf(ee, y3.y, a3.y);               \
    }                                                                           \
}

__global__ __launch_bounds__(256) void k_node(const uint4* __restrict__ xh4,
                                              const float* __restrict__ adst,
                                              const float* __restrict__ par,
                                              const int* __restrict__ deg,
                                              const unsigned int* __restrict__ adj,
                                              const int* __restrict__ perm,
                                              const float* __restrict__ bias,
                                              const float* __restrict__ fc1w,
                                              const float* __restrict__ fc1b,
                                              const float* __restrict__ fc2w,
                                              const float* __restrict__ fc2b,
                                              const float* __restrict__ fc3w,
                                              const float* __restrict__ fc3b,
                                              float* __restrict__ out) {
    __shared__ float Ws[3][900];
    __shared__ float Bs[3][30];
    __shared__ float bias_s[32];
    __shared__ float tb[16 * 32];
    __shared__ int nids[16];
    int t = threadIdx.x;
    {
        const float4* s0 = (const float4*)fc1w;
        const float4* s1 = (const float4*)fc2w;
        const float4* s2 = (const float4*)fc3w;
        for (int i = t; i < 225; i += 256) {
            *(float4*)&Ws[0][i * 4] = s0[i];
            *(float4*)&Ws[1][i * 4] = s1[i];
            *(float4*)&Ws[2][i * 4] = s2[i];
        }
    }
    if (t < 30) { Bs[0][t] = fc1b[t]; Bs[1][t] = fc2b[t]; Bs[2][t] = fc3b[t]; }
    if (t < 32) bias_s[t] = (t < 30) ? bias[t] : 0.f;
    __syncthreads();

    int l = t & 63;
    int k = l & 15;
    int wv = t >> 6;
    int q = (l >> 4) & 3;
    int nl = wv * 4 + q;
    int n = perm[blockIdx.x * 16 + nl];     // degree-sorted node id
    if (k == 0) nids[nl] = n;
    int h = k >> 2;
    int asl_b = (((l & 48) | (k & 12) | 3) << 2);
    int pb4 = (l & 48) << 2;

    float kh = par[64 + h];
    float ew_mean = par[68];
    float adn = adst[n * H_HEADS + h];

    int dn = min(deg[n], MAXDEG);
    int dmax = dn;
    dmax = max(dmax, __shfl_xor(dmax, 16));
    dmax = max(dmax, __shfl_xor(dmax, 32));

    const unsigned int* arow = adj + (size_t)n * MAXDEG;
    unsigned int aw0 = arow[k];
    unsigned int aw1 = 0, aw2 = 0;
    if (dmax > 16) aw1 = arow[16 + k];
    if (dmax > 32) aw2 = arow[32 + k];

    uint4 rw = xh4[(unsigned)n * 16u + (unsigned)k];
    float asn = __uint_as_float((unsigned)__builtin_amdgcn_ds_bpermute(asl_b, (int)rw.w));
    float z = fmaf(ew_mean, kh, adn) + asn;
    z = fmaxf(z, NEG * z);
    float e0 = __expf(z);
    float den = e0;
    float2 x0 = __half22float2(*(const __half2*)&rw.x);
    float2 x1 = __half22float2(*(const __half2*)&rw.y);
    float2 x2 = __half22float2(*(const __half2*)&rw.z);
    float2 x3 = __half22float2(*(const __half2*)&rw.w);
    float2 a0 = make_float2(e0 * x0.x, e0 * x0.y);
    float2 a1 = make_float2(e0 * x1.x, e0 * x1.y);
    float2 a2 = make_float2(e0 * x2.x, e0 * x2.y);
    float2 a3 = make_float2(e0 * x3.x, e0 * x3.y);

    if (dmax > 0) {
        unsigned edA[4], edB[4];
        uint4 rrA[4], rrB[4];
        GISSUE(0, edA, rrA);
        int u0 = 0;
        while (true) {                       // all branches wave-uniform (dmax)
            bool moreB = (u0 + 4 < dmax);
            if (moreB) GISSUE(u0 + 4, edB, rrB);
            GCONSUME(u0, edA, rrA);
            if (!moreB) break;
            bool moreA = (u0 + 8 < dmax);
            if (moreA) GISSUE(u0 + 8, edA, rrA);
            GCONSUME(u0 + 4, edB, rrB);
            if (!moreA) break;
            u0 += 8;
        }
    }

    float rden = 0.25f / (den + 1e-16f);
    a0.x *= rden; a0.y *= rden; a1.x *= rden; a1.y *= rden;
    a2.x *= rden; a2.y *= rden; a3.x *= rden; a3.y *= rden;

    a0.x += __shfl_xor(a0.x, 4); a0.y += __shfl_xor(a0.y, 4);
    a1.x += __shfl_xor(a1.x, 4); a1.y += __shfl_xor(a1.y, 4);
    a2.x += __shfl_xor(a2.x, 4); a2.y += __shfl_xor(a2.y, 4);
    a3.x += __shfl_xor(a3.x, 4); a3.y += __shfl_xor(a3.y, 4);
    a0.x += __shfl_xor(a0.x, 8); a0.y += __shfl_xor(a0.y, 8);
    a1.x += __shfl_xor(a1.x, 8); a1.y += __shfl_xor(a1.y, 8);
    a2.x += __shfl_xor(a2.x, 8); a2.y += __shfl_xor(a2.y, 8);
    a3.x += __shfl_xor(a3.x, 8); a3.y += __shfl_xor(a3.y, 8);

    if ((k & 12) == 0) {
        int ch = k * 8;
        float v0 = fmaxf(a0.x + bias_s[ch + 0], 0.f);
        float v1 = fmaxf(a0.y + bias_s[ch + 1], 0.f);
        float v2 = fmaxf(a1.x + bias_s[ch + 2], 0.f);
        float v3 = fmaxf(a1.y + bias_s[ch + 3], 0.f);
        float v4 = fmaxf(a2.x + bias_s[ch + 4], 0.f);
        float v5 = fmaxf(a2.y + bias_s[ch + 5], 0.f);
        float v6 = fmaxf(a3.x + bias_s[ch + 6], 0.f);
        float v7 = fmaxf(a3.y + bias_s[ch + 7], 0.f);
        float* p = tb + nl * 32 + ch;
        *(float4*)p       = make_float4(v0, v1, v2, v3);
        *(float4*)(p + 4) = make_float4(v4, v5, v6, v7);
    }
    __syncthreads();

    for (int lay = 0; lay < 3; ++lay) {
        float y[2];
#pragma unroll
        for (int j = 0; j < 2; ++j) {
            int i = t + j * 256;
            int nd = i >> 5, c = i & 31;
            y[j] = 0.f;
            if (c < 30) {
                float acc = Bs[lay][c];
                const float* Wl = &Ws[lay][c * 30];
                const float* tr = &tb[nd * 32];
#pragma unroll
                for (int cc = 0; cc < 30; ++cc) acc = fmaf(tr[cc], Wl[cc], acc);
                y[j] = (lay < 2) ? fmaxf(acc, 0.f) : acc;
            }
        }
        __syncthreads();
#pragma unroll
        for (int j = 0; j < 2; ++j) {
            int i = t + j * 256;
            int nd = i >> 5, c = i & 31;
            if (c < 30) {
                if (lay < 2) tb[nd * 32 + c] = y[j];
                else out[(size_t)nids[nd] * 30 + c] = y[j];
            }
        }
        if (lay < 2) __syncthreads();
    }
}

extern "C" void kernel_launch(void* const* d_in, const int* in_sizes, int n_in,
                              void* d_out, int out_size, void* d_ws, size_t ws_size,
                              hipStream_t stream) {
    const float* h        = (const float*)d_in[0];
    const int*   ei       = (const int*)d_in[1];
    const float* ew       = (const float*)d_in[2];
    const float* gamma    = (const float*)d_in[3];
    const float* beta     = (const float*)d_in[4];
    const float* W        = (const float*)d_in[5];
    const float* att_src  = (const float*)d_in[6];
    const float* att_dst  = (const float*)d_in[7];
    const float* att_edge = (const float*)d_in[8];
    const float* Wedge    = (const float*)d_in[9];
    const float* bias     = (const float*)d_in[10];
    const float* fc1w     = (const float*)d_in[11];
    const float* fc1b     = (const float*)d_in[12];
    const float* fc2w     = (const float*)d_in[13];
    const float* fc2b     = (const float*)d_in[14];
    const float* fc3w     = (const float*)d_in[15];
    const float* fc3b     = (const float*)d_in[16];

    float*        ws     = (float*)d_ws;
    unsigned int* xh     = (unsigned int*)(ws + OFF_XH);
    float*        adstb  = ws + OFF_ADST;
    float*        par    = ws + OFF_PAR;
    float*        stats  = ws + OFF_STATS;
    int*          deg    = (int*)(ws + OFF_DEG);
    unsigned int* bcnt_g = (unsigned int*)(ws + OFF_BCNTG);
    unsigned int* adj    = (unsigned int*)(ws + OFF_ADJ);
    uint2*        gbuf   = (uint2*)(ws + OFF_GBUF);
    int*          perm   = (int*)(ws + OFF_PERM);
    float*        out    = (float*)d_out;

    hipMemsetAsync(stats, 0, 64 * 4, stream);

    k_bin<<<BIN_BLOCKS + STATS_BLOCKS, 512, 0, stream>>>(ei, ew, h, bcnt_g, gbuf, stats);
    k_bx<<<BUILD_BLOCKS + X_BLOCKS, 256, 0, stream>>>(bcnt_g, gbuf, adj, deg, perm, h, W,
                                                      Wedge, att_edge, att_src, att_dst,
                                                      gamma, beta, stats, par, xh, adstb);
    k_node<<<NODE_BLOCKS, 256, 0, stream>>>((const uint4*)xh, adstb, par, deg, adj, perm,
                                            bias, fc1w, fc1b, fc2w, fc2b, fc3w, fc3b, out);
}

// Round 18
// 175.564 us; speedup vs baseline: 1.0839x; 1.0839x over previous
//
#include <hip/hip_runtime.h>
#include <hip/hip_fp16.h>

#define N_NODES 100000
#define N_EDGES 1600000
#define D_IN 30
#define H_HEADS 4
#define C_OUT 30
#define EPSV 1e-5f
#define NEG 0.2f
#define MAXDEG 48
#define NPB 128
#define NBUCK 256
#define BUCK_NODES 391        // 256*391 = 100,096 >= N
#define SLICE_CAP 96          // per-(block,bucket); mean 32 (8192/256), P(>96) ~ 0
#define EPB 8192
#define BIN_BLOCKS ((N_EDGES + EPB - 1) / EPB)   // 196 (512-thread blocks)
#define STATS_BLOCKS 224
#define X_BLOCKS ((N_NODES + NPB - 1) / NPB)     // 782
#define NODE_BLOCKS (N_NODES / 16)               // 6250

// ws layout (float offsets) — total ~86 MB (< proven 92)
#define OFF_XH    0            // N*64 u32: 4 heads x {15 fp16x2, fp32 asrc} 256B rows
#define OFF_ADST  6400000      // N*4
#define OFF_PAR   6800000      // 4096
#define OFF_DEG   6804096      // N ints (+pad)
#define OFF_STATS 6904256      // 64
#define OFF_BCNTG 6904320      // BIN_BLOCKS*256 u32 = 50,176 (+pad)
#define OFF_ADJ   6954624      // N*MAXDEG u32
#define OFF_GBUF  11754624     // NBUCK*BIN_BLOCKS*SLICE_CAP uint2 = 9,633,792
#define OFF_PERM  21388416     // N ints

__device__ __forceinline__ float hb2f(unsigned int bits) {
    __half_raw r; r.x = (unsigned short)bits;
    return __half2float(*reinterpret_cast<__half*>(&r));
}

// 512-thread blocks. [0, BIN_BLOCKS): bin 8192 edges into block-private bucket
// slices (mean chunk 32 records = 256B -> good write coalescing) + ew sum.
// Remaining STATS_BLOCKS: BN stats on h only.
__global__ __launch_bounds__(512) void k_bin(const int* __restrict__ ei,
                                             const float* __restrict__ ew,
                                             const float* __restrict__ h,
                                             unsigned int* __restrict__ bcnt_g,
                                             uint2* __restrict__ gbuf,
                                             float* __restrict__ stats) {
    int t = threadIdx.x;
    if (blockIdx.x < BIN_BLOCKS) {
        __shared__ int bcnt[NBUCK];
        if (t < NBUCK) bcnt[t] = 0;
        __syncthreads();
        int blk = blockIdx.x;
        int j0 = blk * EPB + t;
        float es = 0.f;
#pragma unroll
        for (int r = 0; r < 16; ++r) {
            int j = j0 + r * 512;
            if (j < N_EDGES) {
                int s = __builtin_nontemporal_load(ei + j);
                int d = __builtin_nontemporal_load(ei + N_EDGES + j);
                float w = __builtin_nontemporal_load(ew + j);
                es += w;
                __half hv = __float2half_rn(w);
                unsigned short hb = *reinterpret_cast<unsigned short*>(&hv);
                unsigned lo = ((unsigned)s << 15) | (unsigned)(hb & 0x7FFFu);
                int b = d / BUCK_NODES;
                int rank = atomicAdd(&bcnt[b], 1);
                if (rank < SLICE_CAP)
                    gbuf[((size_t)b * BIN_BLOCKS + blk) * SLICE_CAP + rank] =
                        make_uint2(lo, (unsigned)d);
            }
        }
        for (int off = 32; off; off >>= 1) es += __shfl_down(es, off);
        if ((t & 63) == 0) atomicAdd(&stats[60], es);
        __syncthreads();
        if (t < NBUCK) bcnt_g[(size_t)blk * NBUCK + t] = (unsigned)bcnt[t];
        return;
    }
    __shared__ float ls[60];
    if (t < 60) ls[t] = 0.f;
    __syncthreads();
    float s[D_IN], q[D_IN];
#pragma unroll
    for (int d = 0; d < D_IN; ++d) { s[d] = 0.f; q[d] = 0.f; }
    int idx0 = (blockIdx.x - BIN_BLOCKS) * 512 + t;
    int stride = STATS_BLOCKS * 512;
    for (int r = idx0; r < N_NODES; r += stride) {
        const float* row = h + r * D_IN;
#pragma unroll
        for (int d = 0; d < D_IN; ++d) { float v = row[d]; s[d] += v; q[d] += v * v; }
    }
#pragma unroll
    for (int d = 0; d < D_IN; ++d) {
        for (int off = 32; off; off >>= 1) {
            s[d] += __shfl_down(s[d], off);
            q[d] += __shfl_down(q[d], off);
        }
    }
    if ((t & 63) == 0) {
#pragma unroll
        for (int d = 0; d < D_IN; ++d) { atomicAdd(&ls[d], s[d]); atomicAdd(&ls[30 + d], q[d]); }
    }
    __syncthreads();
    if (t < 60) atomicAdd(&stats[t], ls[t]);
}

// blocks [0, 2*NBUCK): build HALF a bucket (196 nodes) in LDS; predicated adj
// writes + degree-DESCENDING perm (R16 proven). Remaining X_BLOCKS: x rows
// (128 nodes/block: W2s fill amortized 2x vs R16) + inline param fold.
__global__ __launch_bounds__(256) void k_bx(const unsigned int* __restrict__ bcnt_g,
                                            const uint2* __restrict__ gbuf,
                                            unsigned int* __restrict__ adj,
                                            int* __restrict__ deg,
                                            int* __restrict__ perm,
                                            const float* __restrict__ h,
                                            const float* __restrict__ W,
                                            const float* __restrict__ Wedge,
                                            const float* __restrict__ att_edge,
                                            const float* __restrict__ att_src,
                                            const float* __restrict__ att_dst,
                                            const float* __restrict__ gamma,
                                            const float* __restrict__ beta,
                                            const float* __restrict__ stats,
                                            float* __restrict__ par,
                                            unsigned int* __restrict__ xh,
                                            float* __restrict__ adst) {
    __shared__ __align__(16) unsigned char smem[38816];
    int t = threadIdx.x;
    if (blockIdx.x < 2 * NBUCK) {
        unsigned* rows = (unsigned*)smem;              // [196*MAXDEG]
        int* cnt = (int*)(smem + 37632);               // [196]
        int* hist = (int*)(smem + 38416);              // [49]
        int* pfx  = (int*)(smem + 38612);              // [49]
        int bb = blockIdx.x;
        int b = bb >> 1, half = bb & 1;
        int lo = b * BUCK_NODES + half * 196;
        int span = half ? (BUCK_NODES - 196) : 196;
        int lim = N_NODES - lo; if (lim > span) lim = span; if (lim < 0) lim = 0;
        for (int i = t; i < 196; i += 256) cnt[i] = 0;
        if (t < 49) hist[t] = 0;
        __syncthreads();
        const uint2* brec = gbuf + (size_t)b * BIN_BLOCKS * SLICE_CAP;
        int totslots = BIN_BLOCKS * SLICE_CAP;         // 18816
        for (int i = t; i < totslots; i += 256) {
            int sl = i / SLICE_CAP;
            int r = i - sl * SLICE_CAP;
            unsigned c = bcnt_g[(size_t)sl * NBUCK + b];
            if (r < (int)c) {
                uint2 rec = brec[i];
                int li = (int)rec.y - lo;
                if (li >= 0 && li < lim) {
                    int p = atomicAdd(&cnt[li], 1);
                    if (p < MAXDEG) rows[li * MAXDEG + p] = rec.x;
                }
            }
        }
        __syncthreads();
        int tot = lim * MAXDEG;
        for (int i = t; i < tot; i += 256) {
            int li = i / MAXDEG;
            int p = i - li * MAXDEG;
            if (p < cnt[li]) adj[(size_t)lo * MAXDEG + i] = rows[i];
        }
        for (int i = t; i < lim; i += 256) {
            int c = cnt[i]; c = (c > MAXDEG) ? MAXDEG : c;
            deg[lo + i] = c;
            atomicAdd(&hist[c], 1);
        }
        __syncthreads();
        if (t == 0) {
            int acc = 0;
            for (int kk = MAXDEG; kk >= 0; --kk) { pfx[kk] = acc; acc += hist[kk]; }
        }
        __syncthreads();
        for (int i = t; i < lim; i += 256) {
            int c = cnt[i]; c = (c > MAXDEG) ? MAXDEG : c;
            int r = atomicAdd(&pfx[c], 1);
            perm[lo + r] = lo + i;
        }
        return;
    }
    float* W2s = (float*)smem;                 // 14400B
    float* hs  = (float*)(smem + 14400);       // 15360B (128*30)
    float* psd = (float*)(smem + 29760);       // 960B
    float* cq  = (float*)(smem + 30720);       // 32B
    float* b2s = (float*)(smem + 30752);       // 480B
    float* scs = (float*)(smem + 31232);       // 120B
    float* shs = (float*)(smem + 31352);       // 120B
    int bx = blockIdx.x - 2 * NBUCK;
    if (t < D_IN) {
        float mu = stats[t] * (1.f / N_NODES);
        float var = stats[30 + t] * (1.f / N_NODES) - mu * mu;
        float inv = 1.f / sqrtf(var + EPSV);
        float sc = gamma[t] * inv;
        scs[t] = sc; shs[t] = beta[t] - mu * sc;
    }
    __syncthreads();
    {   // vectorized: 900 float4; 4|120 so scs index constant per float4
        const float4* W4 = (const float4*)W;
        for (int i = t; i < 900; i += 256) {
            float4 w4 = W4[i];
            float sc = scs[(i * 4) / 120];
            w4.x *= sc; w4.y *= sc; w4.z *= sc; w4.w *= sc;
            *(float4*)&W2s[i * 4] = w4;
        }
    }
    if (t >= 128 && t < 248) {
        int c = t - 128;
        float b = 0.f;
#pragma unroll
        for (int d = 0; d < D_IN; ++d) b = fmaf(shs[d], W[d * 120 + c], b);
        b2s[c] = b;
    }
    if (bx == 0 && t >= 248 && t < 252) {
        int hh = t - 248;
        float k = 0.f;
        for (int c = 0; c < 30; ++c) k = fmaf(Wedge[hh * 30 + c], att_edge[hh * 30 + c], k);
        par[64 + hh] = k;
    }
    if (bx == 0 && t == 252) par[68] = stats[60] * (1.f / N_EDGES);
    __syncthreads();
    int base = bx * NPB;
    int cnt2 = N_NODES - base; if (cnt2 > NPB) cnt2 = NPB;
    if (t < 240) {
        int d = t >> 3, q = t & 7, hh = q & 3;
        const float* att = (q < 4) ? att_src : att_dst;
        float sum = 0.f;
#pragma unroll
        for (int c = 0; c < 30; ++c) sum = fmaf(W2s[d * 120 + hh * 30 + c], att[hh * 30 + c], sum);
        psd[t] = sum;
    }
    if (t >= 240 && t < 248) {
        int q = t - 240, hh = q & 3;
        const float* att = (q < 4) ? att_src : att_dst;
        float sum = 0.f;
#pragma unroll
        for (int c = 0; c < 30; ++c) sum = fmaf(b2s[hh * 30 + c], att[hh * 30 + c], sum);
        cq[q] = sum;
    }
    {   // vectorized h staging (cnt2*30 divisible by 4: cnt2 = 128 or 32)
        const float4* h4 = (const float4*)(h + (size_t)base * 30);
        int n4 = (cnt2 * 30) >> 2;
        for (int i = t; i < n4; i += 256) ((float4*)hs)[i] = h4[i];
    }
    __syncthreads();
    const float2* W2p = (const float2*)W2s;
    int total = cnt2 * 60;
    for (int o = t; o < total; o += 256) {
        int node = o / 60, p = o - node * 60;
        const float* hrow = hs + node * 30;
        float ax = b2s[2 * p], ay = b2s[2 * p + 1];
        const float2* Wp = W2p + p;
#pragma unroll
        for (int d = 0; d < 30; ++d) {
            float hv = hrow[d];
            float2 w = Wp[d * 60];
            ax = fmaf(hv, w.x, ax);
            ay = fmaf(hv, w.y, ay);
        }
        __half2 pk = __float22half2_rn(make_float2(ax, ay));
        int hh = p / 15, j = p - hh * 15;
        xh[(size_t)(base + node) * 64 + hh * 16 + j] = *reinterpret_cast<unsigned int*>(&pk);
    }
    for (int v = t; v < cnt2 * 8; v += 256) {
        int node = v >> 3, q = v & 7;
        const float* hrow = hs + node * 30;
        float sum = cq[q];
#pragma unroll
        for (int d = 0; d < 30; ++d) sum = fmaf(hrow[d], psd[d * 8 + q], sum);
        int n = base + node;
        if (q < 4) xh[(size_t)n * 64 + q * 16 + 15] = __float_as_uint(sum);
        else       adst[n * H_HEADS + (q - 4)] = sum;
    }
}

// R16's k_node exactly (69us measured): degree-sorted, 4-edge batched gather
// (4 dwordx4 in flight), fused bias/ReLU + 3x(30x30) MLP. VGPR 36.
__global__ __launch_bounds__(256) void k_node(const uint4* __restrict__ xh4,
                                              const float* __restrict__ adst,
                                              const float* __restrict__ par,
                                              const int* __restrict__ deg,
                                              const unsigned int* __restrict__ adj,
                                              const int* __restrict__ perm,
                                              const float* __restrict__ bias,
                                              const float* __restrict__ fc1w,
                                              const float* __restrict__ fc1b,
                                              const float* __restrict__ fc2w,
                                              const float* __restrict__ fc2b,
                                              const float* __restrict__ fc3w,
                                              const float* __restrict__ fc3b,
                                              float* __restrict__ out) {
    __shared__ float Ws[3][900];
    __shared__ float Bs[3][30];
    __shared__ float bias_s[32];
    __shared__ float tb[16 * 32];
    __shared__ int nids[16];
    int t = threadIdx.x;
    {
        const float4* s0 = (const float4*)fc1w;
        const float4* s1 = (const float4*)fc2w;
        const float4* s2 = (const float4*)fc3w;
        for (int i = t; i < 225; i += 256) {
            *(float4*)&Ws[0][i * 4] = s0[i];
            *(float4*)&Ws[1][i * 4] = s1[i];
            *(float4*)&Ws[2][i * 4] = s2[i];
        }
    }
    if (t < 30) { Bs[0][t] = fc1b[t]; Bs[1][t] = fc2b[t]; Bs[2][t] = fc3b[t]; }
    if (t < 32) bias_s[t] = (t < 30) ? bias[t] : 0.f;
    __syncthreads();

    int l = t & 63;
    int k = l & 15;
    int wv = t >> 6;
    int q = (l >> 4) & 3;
    int nl = wv * 4 + q;
    int n = perm[blockIdx.x * 16 + nl];
    if (k == 0) nids[nl] = n;
    int h = k >> 2;
    int asl_b = (((l & 48) | (k & 12) | 3) << 2);
    int pb4 = (l & 48) << 2;

    float kh = par[64 + h];
    float ew_mean = par[68];
    float adn = adst[n * H_HEADS + h];

    int dn = min(deg[n], MAXDEG);
    int dmax = dn;
    dmax = max(dmax, __shfl_xor(dmax, 16));
    dmax = max(dmax, __shfl_xor(dmax, 32));

    const unsigned int* arow = adj + (size_t)n * MAXDEG;
    unsigned int aw0 = arow[k];
    unsigned int aw1 = 0, aw2 = 0;
    if (dmax > 16) aw1 = arow[16 + k];
    if (dmax > 32) aw2 = arow[32 + k];

    uint4 rw = xh4[(unsigned)n * 16u + (unsigned)k];
    float asn = __uint_as_float((unsigned)__builtin_amdgcn_ds_bpermute(asl_b, (int)rw.w));
    float z = fmaf(ew_mean, kh, adn) + asn;
    z = fmaxf(z, NEG * z);
    float e0 = __expf(z);
    float den = e0;
    float2 x0 = __half22float2(*(const __half2*)&rw.x);
    float2 x1 = __half22float2(*(const __half2*)&rw.y);
    float2 x2 = __half22float2(*(const __half2*)&rw.z);
    float2 x3 = __half22float2(*(const __half2*)&rw.w);
    float2 a0 = make_float2(e0 * x0.x, e0 * x0.y);
    float2 a1 = make_float2(e0 * x1.x, e0 * x1.y);
    float2 a2 = make_float2(e0 * x2.x, e0 * x2.y);
    float2 a3 = make_float2(e0 * x3.x, e0 * x3.y);

    for (int u0 = 0; u0 < dmax; u0 += 4) {
        unsigned ed[4], ss[4];
        uint4 rr[4];
#pragma unroll
        for (int v = 0; v < 4; ++v) {
            int u = u0 + v;
            unsigned int aw = (u < 16) ? aw0 : ((u < 32) ? aw1 : aw2);
            ed[v] = (unsigned)__builtin_amdgcn_ds_bpermute(pb4 + ((u & 15) << 2), (int)aw);
            ss[v] = (u < dn) ? (ed[v] >> 15) : (unsigned)n;
        }
#pragma unroll
        for (int v = 0; v < 4; ++v) rr[v] = xh4[(size_t)ss[v] * 16u + (unsigned)k];
#pragma unroll
        for (int v = 0; v < 4; ++v) {
            int u = u0 + v;
            bool valid = (u < dn);
            float w = hb2f(ed[v] & 0x7FFFu);
            float as_ = __uint_as_float((unsigned)__builtin_amdgcn_ds_bpermute(asl_b, (int)rr[v].w));
            float zz = fmaf(w, kh, adn) + as_;
            zz = fmaxf(zz, NEG * zz);
            float ee = __expf(zz);
            ee = valid ? ee : 0.f;
            den += ee;
            float2 y0 = __half22float2(*(const __half2*)&rr[v].x);
            float2 y1 = __half22float2(*(const __half2*)&rr[v].y);
            float2 y2 = __half22float2(*(const __half2*)&rr[v].z);
            float2 y3 = __half22float2(*(const __half2*)&rr[v].w);
            a0.x = fmaf(ee, y0.x, a0.x); a0.y = fmaf(ee, y0.y, a0.y);
            a1.x = fmaf(ee, y1.x, a1.x); a1.y = fmaf(ee, y1.y, a1.y);
            a2.x = fmaf(ee, y2.x, a2.x); a2.y = fmaf(ee, y2.y, a2.y);
            a3.x = fmaf(ee, y3.x, a3.x); a3.y = fmaf(ee, y3.y, a3.y);
        }
    }

    float rden = 0.25f / (den + 1e-16f);
    a0.x *= rden; a0.y *= rden; a1.x *= rden; a1.y *= rden;
    a2.x *= rden; a2.y *= rden; a3.x *= rden; a3.y *= rden;

    a0.x += __shfl_xor(a0.x, 4); a0.y += __shfl_xor(a0.y, 4);
    a1.x += __shfl_xor(a1.x, 4); a1.y += __shfl_xor(a1.y, 4);
    a2.x += __shfl_xor(a2.x, 4); a2.y += __shfl_xor(a2.y, 4);
    a3.x += __shfl_xor(a3.x, 4); a3.y += __shfl_xor(a3.y, 4);
    a0.x += __shfl_xor(a0.x, 8); a0.y += __shfl_xor(a0.y, 8);
    a1.x += __shfl_xor(a1.x, 8); a1.y += __shfl_xor(a1.y, 8);
    a2.x += __shfl_xor(a2.x, 8); a2.y += __shfl_xor(a2.y, 8);
    a3.x += __shfl_xor(a3.x, 8); a3.y += __shfl_xor(a3.y, 8);

    if ((k & 12) == 0) {
        int ch = k * 8;
        float v0 = fmaxf(a0.x + bias_s[ch + 0], 0.f);
        float v1 = fmaxf(a0.y + bias_s[ch + 1], 0.f);
        float v2 = fmaxf(a1.x + bias_s[ch + 2], 0.f);
        float v3 = fmaxf(a1.y + bias_s[ch + 3], 0.f);
        float v4 = fmaxf(a2.x + bias_s[ch + 4], 0.f);
        float v5 = fmaxf(a2.y + bias_s[ch + 5], 0.f);
        float v6 = fmaxf(a3.x + bias_s[ch + 6], 0.f);
        float v7 = fmaxf(a3.y + bias_s[ch + 7], 0.f);
        float* p = tb + nl * 32 + ch;
        *(float4*)p       = make_float4(v0, v1, v2, v3);
        *(float4*)(p + 4) = make_float4(v4, v5, v6, v7);
    }
    __syncthreads();

    for (int lay = 0; lay < 3; ++lay) {
        float y[2];
#pragma unroll
        for (int j = 0; j < 2; ++j) {
            int i = t + j * 256;
            int nd = i >> 5, c = i & 31;
            y[j] = 0.f;
            if (c < 30) {
                float acc = Bs[lay][c];
                const float* Wl = &Ws[lay][c * 30];
                const float* tr = &tb[nd * 32];
#pragma unroll
                for (int cc = 0; cc < 30; ++cc) acc = fmaf(tr[cc], Wl[cc], acc);
                y[j] = (lay < 2) ? fmaxf(acc, 0.f) : acc;
            }
        }
        __syncthreads();
#pragma unroll
        for (int j = 0; j < 2; ++j) {
            int i = t + j * 256;
            int nd = i >> 5, c = i & 31;
            if (c < 30) {
                if (lay < 2) tb[nd * 32 + c] = y[j];
                else out[(size_t)nids[nd] * 30 + c] = y[j];
            }
        }
        if (lay < 2) __syncthreads();
    }
}

extern "C" void kernel_launch(void* const* d_in, const int* in_sizes, int n_in,
                              void* d_out, int out_size, void* d_ws, size_t ws_size,
                              hipStream_t stream) {
    const float* h        = (const float*)d_in[0];
    const int*   ei       = (const int*)d_in[1];
    const float* ew       = (const float*)d_in[2];
    const float* gamma    = (const float*)d_in[3];
    const float* beta     = (const float*)d_in[4];
    const float* W        = (const float*)d_in[5];
    const float* att_src  = (const float*)d_in[6];
    const float* att_dst  = (const float*)d_in[7];
    const float* att_edge = (const float*)d_in[8];
    const float* Wedge    = (const float*)d_in[9];
    const float* bias     = (const float*)d_in[10];
    const float* fc1w     = (const float*)d_in[11];
    const float* fc1b     = (const float*)d_in[12];
    const float* fc2w     = (const float*)d_in[13];
    const float* fc2b     = (const float*)d_in[14];
    const float* fc3w     = (const float*)d_in[15];
    const float* fc3b     = (const float*)d_in[16];

    float*        ws     = (float*)d_ws;
    unsigned int* xh     = (unsigned int*)(ws + OFF_XH);
    float*        adstb  = ws + OFF_ADST;
    float*        par    = ws + OFF_PAR;
    float*        stats  = ws + OFF_STATS;
    int*          deg    = (int*)(ws + OFF_DEG);
    unsigned int* bcnt_g = (unsigned int*)(ws + OFF_BCNTG);
    unsigned int* adj    = (unsigned int*)(ws + OFF_ADJ);
    uint2*        gbuf   = (uint2*)(ws + OFF_GBUF);
    int*          perm   = (int*)(ws + OFF_PERM);
    float*        out    = (float*)d_out;

    hipMemsetAsync(stats, 0, 64 * 4, stream);

    k_bin<<<BIN_BLOCKS + STATS_BLOCKS, 512, 0, stream>>>(ei, ew, h, bcnt_g, gbuf, stats);
    k_bx<<<2 * NBUCK + X_BLOCKS, 256, 0, stream>>>(bcnt_g, gbuf, adj, deg, perm, h, W,
                                                   Wedge, att_edge, att_src, att_dst,
                                                   gamma, beta, stats, par, xh, adstb);
    k_node<<<NODE_BLOCKS, 256, 0, stream>>>((const uint4*)xh, adstb, par, deg, adj, perm,
                                            bias, fc1w, fc1b, fc2w, fc2b, fc3w, fc3b, out);
}

// Round 19
// 172.342 us; speedup vs baseline: 1.1042x; 1.0187x over previous
//
#include <hip/hip_runtime.h>
#include <hip/hip_fp16.h>

#define N_NODES 100000
#define N_EDGES 1600000
#define D_IN 30
#define H_HEADS 4
#define C_OUT 30
#define EPSV 1e-5f
#define NEG 0.2f
#define MAXDEG 48
#define NPB 64
#define NBUCK 256
#define BUCK_NODES 391        // 256*391 = 100,096 >= N
#define SLICE_CAP 48          // per-(block,bucket) slice; Poisson(16)+8sigma
#define EPB 4096
#define BIN_BLOCKS ((N_EDGES + EPB - 1) / EPB)   // 391 (512-thread blocks)
#define STATS_BLOCKS 224
#define X_BLOCKS ((N_NODES + NPB - 1) / NPB)     // 1563
#define NODE_BLOCKS (N_NODES / 16)               // 6250

// ws layout (float offsets) — total ~86.6 MB (< proven 92)
#define OFF_XH    0            // N*64 u32: 4 heads x {15 fp16x2, fp32 asrc} 256B rows
#define OFF_ADST  6400000      // N*4
#define OFF_PAR   6800000      // 4096
#define OFF_DEG   6804096      // N ints (+pad)
#define OFF_BCNTG 6904320      // BIN_BLOCKS*256 u32 = 100,096
#define OFF_ADJ   7004416      // N*MAXDEG u32
#define OFF_GBUF  11804416     // NBUCK*BIN_BLOCKS*SLICE_CAP uint2 = 9,609,216
#define OFF_PERM  21413632     // N ints
#define OFF_STATP 21513632     // STATS_BLOCKS*64 = 14,336 (partial BN sums; no init needed)
#define OFF_EWP   21527968     // BIN_BLOCKS floats = 391 (partial ew sums; no init needed)

__device__ __forceinline__ float hb2f(unsigned int bits) {
    __half_raw r; r.x = (unsigned short)bits;
    return __half2float(*reinterpret_cast<__half*>(&r));
}

// 512-thread blocks. [0, BIN_BLOCKS): bin 4096 edges into block-PRIVATE bucket
// slices (LDS rank, zero global atomics) + per-block ew partial sum -> ewp.
// Remaining STATS_BLOCKS: BN partial sums on h -> statp (plain stores; the
// memset dispatch and all global stats atomics are gone).
__global__ __launch_bounds__(512) void k_bin(const int* __restrict__ ei,
                                             const float* __restrict__ ew,
                                             const float* __restrict__ h,
                                             unsigned int* __restrict__ bcnt_g,
                                             uint2* __restrict__ gbuf,
                                             float* __restrict__ statp,
                                             float* __restrict__ ewp) {
    int t = threadIdx.x;
    if (blockIdx.x < BIN_BLOCKS) {
        __shared__ int bcnt[NBUCK];
        __shared__ float ewsum;
        if (t < NBUCK) bcnt[t] = 0;
        if (t == 0) ewsum = 0.f;
        __syncthreads();
        int blk = blockIdx.x;
        int j0 = blk * EPB + t;
        float es = 0.f;
#pragma unroll
        for (int r = 0; r < 8; ++r) {
            int j = j0 + r * 512;
            if (j < N_EDGES) {
                int s = __builtin_nontemporal_load(ei + j);
                int d = __builtin_nontemporal_load(ei + N_EDGES + j);
                float w = __builtin_nontemporal_load(ew + j);
                es += w;
                __half hv = __float2half_rn(w);
                unsigned short hb = *reinterpret_cast<unsigned short*>(&hv);
                unsigned lo = ((unsigned)s << 15) | (unsigned)(hb & 0x7FFFu);
                int b = d / BUCK_NODES;
                int rank = atomicAdd(&bcnt[b], 1);
                if (rank < SLICE_CAP)
                    gbuf[((size_t)b * BIN_BLOCKS + blk) * SLICE_CAP + rank] =
                        make_uint2(lo, (unsigned)d);
            }
        }
        for (int off = 32; off; off >>= 1) es += __shfl_down(es, off);
        if ((t & 63) == 0) atomicAdd(&ewsum, es);
        __syncthreads();
        if (t < NBUCK) bcnt_g[(size_t)blk * NBUCK + t] = (unsigned)bcnt[t];
        if (t == 0) ewp[blk] = ewsum;
        return;
    }
    __shared__ float ls[60];
    if (t < 60) ls[t] = 0.f;
    __syncthreads();
    int sb = blockIdx.x - BIN_BLOCKS;
    float s[D_IN], q[D_IN];
#pragma unroll
    for (int d = 0; d < D_IN; ++d) { s[d] = 0.f; q[d] = 0.f; }
    int idx0 = sb * 512 + t;
    int stride = STATS_BLOCKS * 512;
    for (int r = idx0; r < N_NODES; r += stride) {
        const float* row = h + r * D_IN;
#pragma unroll
        for (int d = 0; d < D_IN; ++d) { float v = row[d]; s[d] += v; q[d] += v * v; }
    }
#pragma unroll
    for (int d = 0; d < D_IN; ++d) {
        for (int off = 32; off; off >>= 1) {
            s[d] += __shfl_down(s[d], off);
            q[d] += __shfl_down(q[d], off);
        }
    }
    if ((t & 63) == 0) {
#pragma unroll
        for (int d = 0; d < D_IN; ++d) { atomicAdd(&ls[d], s[d]); atomicAdd(&ls[30 + d], q[d]); }
    }
    __syncthreads();
    if (t < 60) statp[sb * 64 + t] = ls[t];      // plain store, no init required
}

// blocks [0, 2*NBUCK): build HALF a bucket (196 nodes) in LDS, predicated adj
// writes + degree-DESCENDING perm. Remaining X_BLOCKS: fold statp/ewp (no
// global stats array), then x rows + inline param fold (block 0 -> par).
__global__ __launch_bounds__(256) void k_bx(const unsigned int* __restrict__ bcnt_g,
                                            const uint2* __restrict__ gbuf,
                                            unsigned int* __restrict__ adj,
                                            int* __restrict__ deg,
                                            int* __restrict__ perm,
                                            const float* __restrict__ h,
                                            const float* __restrict__ W,
                                            const float* __restrict__ Wedge,
                                            const float* __restrict__ att_edge,
                                            const float* __restrict__ att_src,
                                            const float* __restrict__ att_dst,
                                            const float* __restrict__ gamma,
                                            const float* __restrict__ beta,
                                            const float* __restrict__ statp,
                                            const float* __restrict__ ewp,
                                            float* __restrict__ par,
                                            unsigned int* __restrict__ xh,
                                            float* __restrict__ adst) {
    __shared__ __align__(16) unsigned char smem[38816];
    int t = threadIdx.x;
    if (blockIdx.x < 2 * NBUCK) {
        unsigned* rows = (unsigned*)smem;              // [196*MAXDEG]
        int* cnt = (int*)(smem + 37632);               // [196]
        int* hist = (int*)(smem + 38416);              // [49]
        int* pfx  = (int*)(smem + 38612);              // [49]
        int bb = blockIdx.x;
        int b = bb >> 1, half = bb & 1;
        int lo = b * BUCK_NODES + half * 196;
        int span = half ? (BUCK_NODES - 196) : 196;
        int lim = N_NODES - lo; if (lim > span) lim = span; if (lim < 0) lim = 0;
        for (int i = t; i < 196; i += 256) cnt[i] = 0;
        if (t < 49) hist[t] = 0;
        __syncthreads();
        const uint2* brec = gbuf + (size_t)b * BIN_BLOCKS * SLICE_CAP;
        int totslots = BIN_BLOCKS * SLICE_CAP;         // 18768
        for (int i = t; i < totslots; i += 256) {
            int sl = i / SLICE_CAP;
            int r = i - sl * SLICE_CAP;
            unsigned c = bcnt_g[(size_t)sl * NBUCK + b];
            if (r < (int)c) {
                uint2 rec = brec[i];
                int li = (int)rec.y - lo;
                if (li >= 0 && li < lim) {
                    int p = atomicAdd(&cnt[li], 1);
                    if (p < MAXDEG) rows[li * MAXDEG + p] = rec.x;
                }
            }
        }
        __syncthreads();
        int tot = lim * MAXDEG;
        for (int i = t; i < tot; i += 256) {
            int li = i / MAXDEG;
            int p = i - li * MAXDEG;
            if (p < cnt[li]) adj[(size_t)lo * MAXDEG + i] = rows[i];
        }
        for (int i = t; i < lim; i += 256) {
            int c = cnt[i]; c = (c > MAXDEG) ? MAXDEG : c;
            deg[lo + i] = c;
            atomicAdd(&hist[c], 1);
        }
        __syncthreads();
        if (t == 0) {
            int acc = 0;
            for (int kk = MAXDEG; kk >= 0; --kk) { pfx[kk] = acc; acc += hist[kk]; }
        }
        __syncthreads();
        for (int i = t; i < lim; i += 256) {
            int c = cnt[i]; c = (c > MAXDEG) ? MAXDEG : c;
            int r = atomicAdd(&pfx[c], 1);
            perm[lo + r] = lo + i;
        }
        return;
    }
    float* W2s = (float*)smem;                 // 3600
    float* hs  = (float*)(smem + 14400);       // 1920
    float* psd = (float*)(smem + 22080);       // 240
    float* cq  = (float*)(smem + 23040);       // 8
    float* b2s = (float*)(smem + 23072);       // 120
    float* scs = (float*)(smem + 23552);       // 30
    float* shs = (float*)(smem + 23672);       // 30
    float* sums = (float*)(smem + 23792);      // 60
    int bx = blockIdx.x - 2 * NBUCK;
    // fold BN partials: thread t<60 sums column t across 224 rows (coalesced)
    if (t < 60) {
        float acc = 0.f;
        for (int i = 0; i < STATS_BLOCKS; ++i) acc += statp[i * 64 + t];
        sums[t] = acc;
    }
    // bx==0: fold ew partials (lanes 192..223, strided) + k_h
    if (bx == 0 && t >= 192 && t < 224) {
        int lane = t - 192;
        float acc = 0.f;
        for (int j = lane; j < BIN_BLOCKS; j += 32) acc += ewp[j];
        for (int off = 16; off; off >>= 1) acc += __shfl_down(acc, off);
        if (lane == 0) par[68] = acc * (1.f / N_EDGES);
    }
    if (bx == 0 && t >= 248 && t < 252) {
        int hh = t - 248;
        float k = 0.f;
        for (int c = 0; c < 30; ++c) k = fmaf(Wedge[hh * 30 + c], att_edge[hh * 30 + c], k);
        par[64 + hh] = k;
    }
    __syncthreads();
    if (t < D_IN) {
        float mu = sums[t] * (1.f / N_NODES);
        float var = sums[30 + t] * (1.f / N_NODES) - mu * mu;
        float inv = 1.f / sqrtf(var + EPSV);
        float sc = gamma[t] * inv;
        scs[t] = sc; shs[t] = beta[t] - mu * sc;
    }
    __syncthreads();
    {   // vectorized: 900 float4; 4|120 so scs index constant per float4
        const float4* W4 = (const float4*)W;
        for (int i = t; i < 900; i += 256) {
            float4 w4 = W4[i];
            float sc = scs[(i * 4) / 120];
            w4.x *= sc; w4.y *= sc; w4.z *= sc; w4.w *= sc;
            *(float4*)&W2s[i * 4] = w4;
        }
    }
    if (t >= 128 && t < 248) {
        int c = t - 128;
        float b = 0.f;
#pragma unroll
        for (int d = 0; d < D_IN; ++d) b = fmaf(shs[d], W[d * 120 + c], b);
        b2s[c] = b;
    }
    __syncthreads();
    int base = bx * NPB;
    int cnt2 = N_NODES - base; if (cnt2 > NPB) cnt2 = NPB;
    if (t < 240) {
        int d = t >> 3, q = t & 7, hh = q & 3;
        const float* att = (q < 4) ? att_src : att_dst;
        float sum = 0.f;
#pragma unroll
        for (int c = 0; c < 30; ++c) sum = fmaf(W2s[d * 120 + hh * 30 + c], att[hh * 30 + c], sum);
        psd[t] = sum;
    }
    if (t >= 240 && t < 248) {
        int q = t - 240, hh = q & 3;
        const float* att = (q < 4) ? att_src : att_dst;
        float sum = 0.f;
#pragma unroll
        for (int c = 0; c < 30; ++c) sum = fmaf(b2s[hh * 30 + c], att[hh * 30 + c], sum);
        cq[q] = sum;
    }
    {   // vectorized h staging
        const float4* h4 = (const float4*)(h + (size_t)base * 30);
        int n4 = (cnt2 * 30) >> 2;
        for (int i = t; i < n4; i += 256) ((float4*)hs)[i] = h4[i];
    }
    __syncthreads();
    const float2* W2p = (const float2*)W2s;
    int total = cnt2 * 60;
    for (int o = t; o < total; o += 256) {
        int node = o / 60, p = o - node * 60;
        const float* hrow = hs + node * 30;
        float ax = b2s[2 * p], ay = b2s[2 * p + 1];
        const float2* Wp = W2p + p;
#pragma unroll
        for (int d = 0; d < 30; ++d) {
            float hv = hrow[d];
            float2 w = Wp[d * 60];
            ax = fmaf(hv, w.x, ax);
            ay = fmaf(hv, w.y, ay);
        }
        __half2 pk = __float22half2_rn(make_float2(ax, ay));
        int hh = p / 15, j = p - hh * 15;
        xh[(size_t)(base + node) * 64 + hh * 16 + j] = *reinterpret_cast<unsigned int*>(&pk);
    }
    for (int v = t; v < cnt2 * 8; v += 256) {
        int node = v >> 3, q = v & 7;
        const float* hrow = hs + node * 30;
        float sum = cq[q];
#pragma unroll
        for (int d = 0; d < 30; ++d) sum = fmaf(hrow[d], psd[d * 8 + q], sum);
        int n = base + node;
        if (q < 4) xh[(size_t)n * 64 + q * 16 + 15] = __float_as_uint(sum);
        else       adst[n * H_HEADS + (q - 4)] = sum;
    }
}

// R16's k_node exactly (69us proven): degree-sorted, 4-edge batched gather
// (4 dwordx4 in flight), fused bias/ReLU + 3x(30x30) MLP. VGPR 36.
__global__ __launch_bounds__(256) void k_node(const uint4* __restrict__ xh4,
                                              const float* __restrict__ adst,
                                              const float* __restrict__ par,
                                              const int* __restrict__ deg,
                                              const unsigned int* __restrict__ adj,
                                              const int* __restrict__ perm,
                                              const float* __restrict__ bias,
                                              const float* __restrict__ fc1w,
                                              const float* __restrict__ fc1b,
                                              const float* __restrict__ fc2w,
                                              const float* __restrict__ fc2b,
                                              const float* __restrict__ fc3w,
                                              const float* __restrict__ fc3b,
                                              float* __restrict__ out) {
    __shared__ float Ws[3][900];
    __shared__ float Bs[3][30];
    __shared__ float bias_s[32];
    __shared__ float tb[16 * 32];
    __shared__ int nids[16];
    int t = threadIdx.x;
    {
        const float4* s0 = (const float4*)fc1w;
        const float4* s1 = (const float4*)fc2w;
        const float4* s2 = (const float4*)fc3w;
        for (int i = t; i < 225; i += 256) {
            *(float4*)&Ws[0][i * 4] = s0[i];
            *(float4*)&Ws[1][i * 4] = s1[i];
            *(float4*)&Ws[2][i * 4] = s2[i];
        }
    }
    if (t < 30) { Bs[0][t] = fc1b[t]; Bs[1][t] = fc2b[t]; Bs[2][t] = fc3b[t]; }
    if (t < 32) bias_s[t] = (t < 30) ? bias[t] : 0.f;
    __syncthreads();

    int l = t & 63;
    int k = l & 15;
    int wv = t >> 6;
    int q = (l >> 4) & 3;
    int nl = wv * 4 + q;
    int n = perm[blockIdx.x * 16 + nl];
    if (k == 0) nids[nl] = n;
    int h = k >> 2;
    int asl_b = (((l & 48) | (k & 12) | 3) << 2);
    int pb4 = (l & 48) << 2;

    float kh = par[64 + h];
    float ew_mean = par[68];
    float adn = adst[n * H_HEADS + h];

    int dn = min(deg[n], MAXDEG);
    int dmax = dn;
    dmax = max(dmax, __shfl_xor(dmax, 16));
    dmax = max(dmax, __shfl_xor(dmax, 32));

    const unsigned int* arow = adj + (size_t)n * MAXDEG;
    unsigned int aw0 = arow[k];
    unsigned int aw1 = 0, aw2 = 0;
    if (dmax > 16) aw1 = arow[16 + k];
    if (dmax > 32) aw2 = arow[32 + k];

    uint4 rw = xh4[(unsigned)n * 16u + (unsigned)k];
    float asn = __uint_as_float((unsigned)__builtin_amdgcn_ds_bpermute(asl_b, (int)rw.w));
    float z = fmaf(ew_mean, kh, adn) + asn;
    z = fmaxf(z, NEG * z);
    float e0 = __expf(z);
    float den = e0;
    float2 x0 = __half22float2(*(const __half2*)&rw.x);
    float2 x1 = __half22float2(*(const __half2*)&rw.y);
    float2 x2 = __half22float2(*(const __half2*)&rw.z);
    float2 x3 = __half22float2(*(const __half2*)&rw.w);
    float2 a0 = make_float2(e0 * x0.x, e0 * x0.y);
    float2 a1 = make_float2(e0 * x1.x, e0 * x1.y);
    float2 a2 = make_float2(e0 * x2.x, e0 * x2.y);
    float2 a3 = make_float2(e0 * x3.x, e0 * x3.y);

    for (int u0 = 0; u0 < dmax; u0 += 4) {
        unsigned ed[4], ss[4];
        uint4 rr[4];
#pragma unroll
        for (int v = 0; v < 4; ++v) {
            int u = u0 + v;
            unsigned int aw = (u < 16) ? aw0 : ((u < 32) ? aw1 : aw2);
            ed[v] = (unsigned)__builtin_amdgcn_ds_bpermute(pb4 + ((u & 15) << 2), (int)aw);
            ss[v] = (u < dn) ? (ed[v] >> 15) : (unsigned)n;
        }
#pragma unroll
        for (int v = 0; v < 4; ++v) rr[v] = xh4[(size_t)ss[v] * 16u + (unsigned)k];
#pragma unroll
        for (int v = 0; v < 4; ++v) {
            int u = u0 + v;
            bool valid = (u < dn);
            float w = hb2f(ed[v] & 0x7FFFu);
            float as_ = __uint_as_float((unsigned)__builtin_amdgcn_ds_bpermute(asl_b, (int)rr[v].w));
            float zz = fmaf(w, kh, adn) + as_;
            zz = fmaxf(zz, NEG * zz);
            float ee = __expf(zz);
            ee = valid ? ee : 0.f;
            den += ee;
            float2 y0 = __half22float2(*(const __half2*)&rr[v].x);
            float2 y1 = __half22float2(*(const __half2*)&rr[v].y);
            float2 y2 = __half22float2(*(const __half2*)&rr[v].z);
            float2 y3 = __half22float2(*(const __half2*)&rr[v].w);
            a0.x = fmaf(ee, y0.x, a0.x); a0.y = fmaf(ee, y0.y, a0.y);
            a1.x = fmaf(ee, y1.x, a1.x); a1.y = fmaf(ee, y1.y, a1.y);
            a2.x = fmaf(ee, y2.x, a2.x); a2.y = fmaf(ee, y2.y, a2.y);
            a3.x = fmaf(ee, y3.x, a3.x); a3.y = fmaf(ee, y3.y, a3.y);
        }
    }

    float rden = 0.25f / (den + 1e-16f);
    a0.x *= rden; a0.y *= rden; a1.x *= rden; a1.y *= rden;
    a2.x *= rden; a2.y *= rden; a3.x *= rden; a3.y *= rden;

    a0.x += __shfl_xor(a0.x, 4); a0.y += __shfl_xor(a0.y, 4);
    a1.x += __shfl_xor(a1.x, 4); a1.y += __shfl_xor(a1.y, 4);
    a2.x += __shfl_xor(a2.x, 4); a2.y += __shfl_xor(a2.y, 4);
    a3.x += __shfl_xor(a3.x, 4); a3.y += __shfl_xor(a3.y, 4);
    a0.x += __shfl_xor(a0.x, 8); a0.y += __shfl_xor(a0.y, 8);
    a1.x += __shfl_xor(a1.x, 8); a1.y += __shfl_xor(a1.y, 8);
    a2.x += __shfl_xor(a2.x, 8); a2.y += __shfl_xor(a2.y, 8);
    a3.x += __shfl_xor(a3.x, 8); a3.y += __shfl_xor(a3.y, 8);

    if ((k & 12) == 0) {
        int ch = k * 8;
        float v0 = fmaxf(a0.x + bias_s[ch + 0], 0.f);
        float v1 = fmaxf(a0.y + bias_s[ch + 1], 0.f);
        float v2 = fmaxf(a1.x + bias_s[ch + 2], 0.f);
        float v3 = fmaxf(a1.y + bias_s[ch + 3], 0.f);
        float v4 = fmaxf(a2.x + bias_s[ch + 4], 0.f);
        float v5 = fmaxf(a2.y + bias_s[ch + 5], 0.f);
        float v6 = fmaxf(a3.x + bias_s[ch + 6], 0.f);
        float v7 = fmaxf(a3.y + bias_s[ch + 7], 0.f);
        float* p = tb + nl * 32 + ch;
        *(float4*)p       = make_float4(v0, v1, v2, v3);
        *(float4*)(p + 4) = make_float4(v4, v5, v6, v7);
    }
    __syncthreads();

    for (int lay = 0; lay < 3; ++lay) {
        float y[2];
#pragma unroll
        for (int j = 0; j < 2; ++j) {
            int i = t + j * 256;
            int nd = i >> 5, c = i & 31;
            y[j] = 0.f;
            if (c < 30) {
                float acc = Bs[lay][c];
                const float* Wl = &Ws[lay][c * 30];
                const float* tr = &tb[nd * 32];
#pragma unroll
                for (int cc = 0; cc < 30; ++cc) acc = fmaf(tr[cc], Wl[cc], acc);
                y[j] = (lay < 2) ? fmaxf(acc, 0.f) : acc;
            }
        }
        __syncthreads();
#pragma unroll
        for (int j = 0; j < 2; ++j) {
            int i = t + j * 256;
            int nd = i >> 5, c = i & 31;
            if (c < 30) {
                if (lay < 2) tb[nd * 32 + c] = y[j];
                else out[(size_t)nids[nd] * 30 + c] = y[j];
            }
        }
        if (lay < 2) __syncthreads();
    }
}

extern "C" void kernel_launch(void* const* d_in, const int* in_sizes, int n_in,
                              void* d_out, int out_size, void* d_ws, size_t ws_size,
                              hipStream_t stream) {
    const float* h        = (const float*)d_in[0];
    const int*   ei       = (const int*)d_in[1];
    const float* ew       = (const float*)d_in[2];
    const float* gamma    = (const float*)d_in[3];
    const float* beta     = (const float*)d_in[4];
    const float* W        = (const float*)d_in[5];
    const float* att_src  = (const float*)d_in[6];
    const float* att_dst  = (const float*)d_in[7];
    const float* att_edge = (const float*)d_in[8];
    const float* Wedge    = (const float*)d_in[9];
    const float* bias     = (const float*)d_in[10];
    const float* fc1w     = (const float*)d_in[11];
    const float* fc1b     = (const float*)d_in[12];
    const float* fc2w     = (const float*)d_in[13];
    const float* fc2b     = (const float*)d_in[14];
    const float* fc3w     = (const float*)d_in[15];
    const float* fc3b     = (const float*)d_in[16];

    float*        ws     = (float*)d_ws;
    unsigned int* xh     = (unsigned int*)(ws + OFF_XH);
    float*        adstb  = ws + OFF_ADST;
    float*        par    = ws + OFF_PAR;
    int*          deg    = (int*)(ws + OFF_DEG);
    unsigned int* bcnt_g = (unsigned int*)(ws + OFF_BCNTG);
    unsigned int* adj    = (unsigned int*)(ws + OFF_ADJ);
    uint2*        gbuf   = (uint2*)(ws + OFF_GBUF);
    int*          perm   = (int*)(ws + OFF_PERM);
    float*        statp  = ws + OFF_STATP;
    float*        ewp    = ws + OFF_EWP;
    float*        out    = (float*)d_out;

    k_bin<<<BIN_BLOCKS + STATS_BLOCKS, 512, 0, stream>>>(ei, ew, h, bcnt_g, gbuf,
                                                         statp, ewp);
    k_bx<<<2 * NBUCK + X_BLOCKS, 256, 0, stream>>>(bcnt_g, gbuf, adj, deg, perm, h, W,
                                                   Wedge, att_edge, att_src, att_dst,
                                                   gamma, beta, statp, ewp, par, xh, adstb);
    k_node<<<NODE_BLOCKS, 256, 0, stream>>>((const uint4*)xh, adstb, par, deg, adj, perm,
                                            bias, fc1w, fc1b, fc2w, fc2b, fc3w, fc3b, out);
}

// Round 20
// 163.073 us; speedup vs baseline: 1.1670x; 1.0568x over previous
//
#include <hip/hip_runtime.h>
#include <hip/hip_fp16.h>

#define N_NODES 100000
#define N_EDGES 1600000
#define D_IN 30
#define H_HEADS 4
#define C_OUT 30
#define EPSV 1e-5f
#define NEG 0.2f
#define MAXDEG 48
#define NPB 64
#define NBUCK 256
#define BUCK_NODES 391        // 256*391 = 100,096 >= N
#define SLICE_CAP 48          // per-(block,bucket) slice; Poisson(16)+8sigma
#define EPB 4096
#define BIN_BLOCKS ((N_EDGES + EPB - 1) / EPB)   // 391 (512-thread blocks)
#define STATS_BLOCKS 224
#define X_BLOCKS ((N_NODES + NPB - 1) / NPB)     // 1563
#define NODE_BLOCKS (N_NODES / 16)               // 6250

// ws layout (float offsets) — total ~86.6 MB (< proven 92)
#define OFF_XH    0            // N*64 u32: 4 heads x {15 fp16x2, fp32 asrc} 256B rows
#define OFF_ADST  6400000      // N*4
#define OFF_PAR   6800000      // 4096
#define OFF_DEG   6804096      // N ints (+pad)
#define OFF_BCNTG 6904320      // BIN_BLOCKS*256 u32 = 100,096
#define OFF_ADJ   7004416      // N*MAXDEG u32
#define OFF_GBUF  11804416     // NBUCK*BIN_BLOCKS*SLICE_CAP uint2 = 9,609,216
#define OFF_PERM  21413632     // N ints
#define OFF_STATP 21513632     // STATS_BLOCKS*64 (partial BN sums; no init needed)
#define OFF_EWP   21527968     // BIN_BLOCKS floats (partial ew sums; no init needed)

__device__ __forceinline__ float hb2f(unsigned int bits) {
    __half_raw r; r.x = (unsigned short)bits;
    return __half2float(*reinterpret_cast<__half*>(&r));
}

// 512-thread blocks. [0, BIN_BLOCKS): bin 4096 edges into block-PRIVATE bucket
// slices (LDS rank, zero global atomics) + per-block ew partial sum -> ewp.
// Remaining STATS_BLOCKS: BN partial sums on h -> statp (plain stores).
__global__ __launch_bounds__(512) void k_bin(const int* __restrict__ ei,
                                             const float* __restrict__ ew,
                                             const float* __restrict__ h,
                                             unsigned int* __restrict__ bcnt_g,
                                             uint2* __restrict__ gbuf,
                                             float* __restrict__ statp,
                                             float* __restrict__ ewp) {
    int t = threadIdx.x;
    if (blockIdx.x < BIN_BLOCKS) {
        __shared__ int bcnt[NBUCK];
        __shared__ float ewsum;
        if (t < NBUCK) bcnt[t] = 0;
        if (t == 0) ewsum = 0.f;
        __syncthreads();
        int blk = blockIdx.x;
        int j0 = blk * EPB + t;
        float es = 0.f;
#pragma unroll
        for (int r = 0; r < 8; ++r) {
            int j = j0 + r * 512;
            if (j < N_EDGES) {
                int s = __builtin_nontemporal_load(ei + j);
                int d = __builtin_nontemporal_load(ei + N_EDGES + j);
                float w = __builtin_nontemporal_load(ew + j);
                es += w;
                __half hv = __float2half_rn(w);
                unsigned short hb = *reinterpret_cast<unsigned short*>(&hv);
                unsigned lo = ((unsigned)s << 15) | (unsigned)(hb & 0x7FFFu);
                int b = d / BUCK_NODES;
                int rank = atomicAdd(&bcnt[b], 1);
                if (rank < SLICE_CAP)
                    gbuf[((size_t)b * BIN_BLOCKS + blk) * SLICE_CAP + rank] =
                        make_uint2(lo, (unsigned)d);
            }
        }
        for (int off = 32; off; off >>= 1) es += __shfl_down(es, off);
        if ((t & 63) == 0) atomicAdd(&ewsum, es);
        __syncthreads();
        if (t < NBUCK) bcnt_g[(size_t)blk * NBUCK + t] = (unsigned)bcnt[t];
        if (t == 0) ewp[blk] = ewsum;
        return;
    }
    __shared__ float ls[60];
    if (t < 60) ls[t] = 0.f;
    __syncthreads();
    int sb = blockIdx.x - BIN_BLOCKS;
    float s[D_IN], q[D_IN];
#pragma unroll
    for (int d = 0; d < D_IN; ++d) { s[d] = 0.f; q[d] = 0.f; }
    int idx0 = sb * 512 + t;
    int stride = STATS_BLOCKS * 512;
    for (int r = idx0; r < N_NODES; r += stride) {
        const float* row = h + r * D_IN;
#pragma unroll
        for (int d = 0; d < D_IN; ++d) { float v = row[d]; s[d] += v; q[d] += v * v; }
    }
#pragma unroll
    for (int d = 0; d < D_IN; ++d) {
        for (int off = 32; off; off >>= 1) {
            s[d] += __shfl_down(s[d], off);
            q[d] += __shfl_down(q[d], off);
        }
    }
    if ((t & 63) == 0) {
#pragma unroll
        for (int d = 0; d < D_IN; ++d) { atomicAdd(&ls[d], s[d]); atomicAdd(&ls[30 + d], q[d]); }
    }
    __syncthreads();
    if (t < 60) statp[sb * 64 + t] = ls[t];
}

// blocks [0, 2*NBUCK): build HALF a bucket (196 nodes) — cnt in LDS, adj
// entries stored DIRECTLY to global (L2-resident 75KB window; no rows staging,
// smem 38.9KB -> 24KB -> occupancy 4 -> 6 blocks/CU). Emits degree-DESCENDING
// perm. Remaining X_BLOCKS: fold statp/ewp, x rows + inline param fold.
__global__ __launch_bounds__(256) void k_bx(const unsigned int* __restrict__ bcnt_g,
                                            const uint2* __restrict__ gbuf,
                                            unsigned int* __restrict__ adj,
                                            int* __restrict__ deg,
                                            int* __restrict__ perm,
                                            const float* __restrict__ h,
                                            const float* __restrict__ W,
                                            const float* __restrict__ Wedge,
                                            const float* __restrict__ att_edge,
                                            const float* __restrict__ att_src,
                                            const float* __restrict__ att_dst,
                                            const float* __restrict__ gamma,
                                            const float* __restrict__ beta,
                                            const float* __restrict__ statp,
                                            const float* __restrict__ ewp,
                                            float* __restrict__ par,
                                            unsigned int* __restrict__ xh,
                                            float* __restrict__ adst) {
    __shared__ __align__(16) unsigned char smem[24064];
    int t = threadIdx.x;
    if (blockIdx.x < 2 * NBUCK) {
        int* cnt  = (int*)smem;                        // [196]
        int* hist = (int*)(smem + 784);                // [49]
        int* pfx  = (int*)(smem + 980);                // [49]
        int bb = blockIdx.x;
        int b = bb >> 1, half = bb & 1;
        int lo = b * BUCK_NODES + half * 196;
        int span = half ? (BUCK_NODES - 196) : 196;
        int lim = N_NODES - lo; if (lim > span) lim = span; if (lim < 0) lim = 0;
        for (int i = t; i < 196; i += 256) cnt[i] = 0;
        if (t < 49) hist[t] = 0;
        __syncthreads();
        const uint2* brec = gbuf + (size_t)b * BIN_BLOCKS * SLICE_CAP;
        int totslots = BIN_BLOCKS * SLICE_CAP;         // 18768
        for (int i = t; i < totslots; i += 256) {
            int sl = i / SLICE_CAP;
            int r = i - sl * SLICE_CAP;
            unsigned c = bcnt_g[(size_t)sl * NBUCK + b];
            if (r < (int)c) {
                uint2 rec = brec[i];
                int li = (int)rec.y - lo;
                if (li >= 0 && li < lim) {
                    int p = atomicAdd(&cnt[li], 1);
                    if (p < MAXDEG)
                        adj[(size_t)(lo + li) * MAXDEG + p] = rec.x;  // direct, L2-hot
                }
            }
        }
        __syncthreads();
        for (int i = t; i < lim; i += 256) {
            int c = cnt[i]; c = (c > MAXDEG) ? MAXDEG : c;
            deg[lo + i] = c;
            atomicAdd(&hist[c], 1);
        }
        __syncthreads();
        if (t == 0) {
            int acc = 0;
            for (int kk = MAXDEG; kk >= 0; --kk) { pfx[kk] = acc; acc += hist[kk]; }
        }
        __syncthreads();
        for (int i = t; i < lim; i += 256) {
            int c = cnt[i]; c = (c > MAXDEG) ? MAXDEG : c;
            int r = atomicAdd(&pfx[c], 1);
            perm[lo + r] = lo + i;
        }
        return;
    }
    float* W2s = (float*)smem;                 // 14400B
    float* hs  = (float*)(smem + 14400);       // 7680B
    float* psd = (float*)(smem + 22080);       // 960B
    float* cq  = (float*)(smem + 23040);       // 32B
    float* b2s = (float*)(smem + 23072);       // 480B
    float* scs = (float*)(smem + 23552);       // 120B
    float* shs = (float*)(smem + 23672);       // 120B
    float* sums = (float*)(smem + 23792);      // 240B
    int bx = blockIdx.x - 2 * NBUCK;
    if (t < 60) {
        float acc = 0.f;
        for (int i = 0; i < STATS_BLOCKS; ++i) acc += statp[i * 64 + t];
        sums[t] = acc;
    }
    if (bx == 0 && t >= 192 && t < 224) {
        int lane = t - 192;
        float acc = 0.f;
        for (int j = lane; j < BIN_BLOCKS; j += 32) acc += ewp[j];
        for (int off = 16; off; off >>= 1) acc += __shfl_down(acc, off);
        if (lane == 0) par[68] = acc * (1.f / N_EDGES);
    }
    if (bx == 0 && t >= 248 && t < 252) {
        int hh = t - 248;
        float k = 0.f;
        for (int c = 0; c < 30; ++c) k = fmaf(Wedge[hh * 30 + c], att_edge[hh * 30 + c], k);
        par[64 + hh] = k;
    }
    __syncthreads();
    if (t < D_IN) {
        float mu = sums[t] * (1.f / N_NODES);
        float var = sums[30 + t] * (1.f / N_NODES) - mu * mu;
        float inv = 1.f / sqrtf(var + EPSV);
        float sc = gamma[t] * inv;
        scs[t] = sc; shs[t] = beta[t] - mu * sc;
    }
    __syncthreads();
    {
        const float4* W4 = (const float4*)W;
        for (int i = t; i < 900; i += 256) {
            float4 w4 = W4[i];
            float sc = scs[(i * 4) / 120];
            w4.x *= sc; w4.y *= sc; w4.z *= sc; w4.w *= sc;
            *(float4*)&W2s[i * 4] = w4;
        }
    }
    if (t >= 128 && t < 248) {
        int c = t - 128;
        float b = 0.f;
#pragma unroll
        for (int d = 0; d < D_IN; ++d) b = fmaf(shs[d], W[d * 120 + c], b);
        b2s[c] = b;
    }
    __syncthreads();
    int base = bx * NPB;
    int cnt2 = N_NODES - base; if (cnt2 > NPB) cnt2 = NPB;
    if (t < 240) {
        int d = t >> 3, q = t & 7, hh = q & 3;
        const float* att = (q < 4) ? att_src : att_dst;
        float sum = 0.f;
#pragma unroll
        for (int c = 0; c < 30; ++c) sum = fmaf(W2s[d * 120 + hh * 30 + c], att[hh * 30 + c], sum);
        psd[t] = sum;
    }
    if (t >= 240 && t < 248) {
        int q = t - 240, hh = q & 3;
        const float* att = (q < 4) ? att_src : att_dst;
        float sum = 0.f;
#pragma unroll
        for (int c = 0; c < 30; ++c) sum = fmaf(b2s[hh * 30 + c], att[hh * 30 + c], sum);
        cq[q] = sum;
    }
    {
        const float4* h4 = (const float4*)(h + (size_t)base * 30);
        int n4 = (cnt2 * 30) >> 2;
        for (int i = t; i < n4; i += 256) ((float4*)hs)[i] = h4[i];
    }
    __syncthreads();
    const float2* W2p = (const float2*)W2s;
    int total = cnt2 * 60;
    for (int o = t; o < total; o += 256) {
        int node = o / 60, p = o - node * 60;
        const float* hrow = hs + node * 30;
        float ax = b2s[2 * p], ay = b2s[2 * p + 1];
        const float2* Wp = W2p + p;
#pragma unroll
        for (int d = 0; d < 30; ++d) {
            float hv = hrow[d];
            float2 w = Wp[d * 60];
            ax = fmaf(hv, w.x, ax);
            ay = fmaf(hv, w.y, ay);
        }
        __half2 pk = __float22half2_rn(make_float2(ax, ay));
        int hh = p / 15, j = p - hh * 15;
        xh[(size_t)(base + node) * 64 + hh * 16 + j] = *reinterpret_cast<unsigned int*>(&pk);
    }
    for (int v = t; v < cnt2 * 8; v += 256) {
        int node = v >> 3, q = v & 7;
        const float* hrow = hs + node * 30;
        float sum = cq[q];
#pragma unroll
        for (int d = 0; d < 30; ++d) sum = fmaf(hrow[d], psd[d * 8 + q], sum);
        int n = base + node;
        if (q < 4) xh[(size_t)n * 64 + q * 16 + 15] = __float_as_uint(sum);
        else       adst[n * H_HEADS + (q - 4)] = sum;
    }
}

// R16's k_node exactly (69us proven): degree-sorted, 4-edge batched gather
// (4 dwordx4 in flight), fused bias/ReLU + 3x(30x30) MLP. VGPR 36.
__global__ __launch_bounds__(256) void k_node(const uint4* __restrict__ xh4,
                                              const float* __restrict__ adst,
                                              const float* __restrict__ par,
                                              const int* __restrict__ deg,
                                              const unsigned int* __restrict__ adj,
                                              const int* __restrict__ perm,
                                              const float* __restrict__ bias,
                                              const float* __restrict__ fc1w,
                                              const float* __restrict__ fc1b,
                                              const float* __restrict__ fc2w,
                                              const float* __restrict__ fc2b,
                                              const float* __restrict__ fc3w,
                                              const float* __restrict__ fc3b,
                                              float* __restrict__ out) {
    __shared__ float Ws[3][900];
    __shared__ float Bs[3][30];
    __shared__ float bias_s[32];
    __shared__ float tb[16 * 32];
    __shared__ int nids[16];
    int t = threadIdx.x;
    {
        const float4* s0 = (const float4*)fc1w;
        const float4* s1 = (const float4*)fc2w;
        const float4* s2 = (const float4*)fc3w;
        for (int i = t; i < 225; i += 256) {
            *(float4*)&Ws[0][i * 4] = s0[i];
            *(float4*)&Ws[1][i * 4] = s1[i];
            *(float4*)&Ws[2][i * 4] = s2[i];
        }
    }
    if (t < 30) { Bs[0][t] = fc1b[t]; Bs[1][t] = fc2b[t]; Bs[2][t] = fc3b[t]; }
    if (t < 32) bias_s[t] = (t < 30) ? bias[t] : 0.f;
    __syncthreads();

    int l = t & 63;
    int k = l & 15;
    int wv = t >> 6;
    int q = (l >> 4) & 3;
    int nl = wv * 4 + q;
    int n = perm[blockIdx.x * 16 + nl];
    if (k == 0) nids[nl] = n;
    int h = k >> 2;
    int asl_b = (((l & 48) | (k & 12) | 3) << 2);
    int pb4 = (l & 48) << 2;

    float kh = par[64 + h];
    float ew_mean = par[68];
    float adn = adst[n * H_HEADS + h];

    int dn = min(deg[n], MAXDEG);
    int dmax = dn;
    dmax = max(dmax, __shfl_xor(dmax, 16));
    dmax = max(dmax, __shfl_xor(dmax, 32));

    const unsigned int* arow = adj + (size_t)n * MAXDEG;
    unsigned int aw0 = arow[k];
    unsigned int aw1 = 0, aw2 = 0;
    if (dmax > 16) aw1 = arow[16 + k];
    if (dmax > 32) aw2 = arow[32 + k];

    uint4 rw = xh4[(unsigned)n * 16u + (unsigned)k];
    float asn = __uint_as_float((unsigned)__builtin_amdgcn_ds_bpermute(asl_b, (int)rw.w));
    float z = fmaf(ew_mean, kh, adn) + asn;
    z = fmaxf(z, NEG * z);
    float e0 = __expf(z);
    float den = e0;
    float2 x0 = __half22float2(*(const __half2*)&rw.x);
    float2 x1 = __half22float2(*(const __half2*)&rw.y);
    float2 x2 = __half22float2(*(const __half2*)&rw.z);
    float2 x3 = __half22float2(*(const __half2*)&rw.w);
    float2 a0 = make_float2(e0 * x0.x, e0 * x0.y);
    float2 a1 = make_float2(e0 * x1.x, e0 * x1.y);
    float2 a2 = make_float2(e0 * x2.x, e0 * x2.y);
    float2 a3 = make_float2(e0 * x3.x, e0 * x3.y);

    for (int u0 = 0; u0 < dmax; u0 += 4) {
        unsigned ed[4], ss[4];
        uint4 rr[4];
#pragma unroll
        for (int v = 0; v < 4; ++v) {
            int u = u0 + v;
            unsigned int aw = (u < 16) ? aw0 : ((u < 32) ? aw1 : aw2);
            ed[v] = (unsigned)__builtin_amdgcn_ds_bpermute(pb4 + ((u & 15) << 2), (int)aw);
            ss[v] = (u < dn) ? (ed[v] >> 15) : (unsigned)n;
        }
#pragma unroll
        for (int v = 0; v < 4; ++v) rr[v] = xh4[(size_t)ss[v] * 16u + (unsigned)k];
#pragma unroll
        for (int v = 0; v < 4; ++v) {
            int u = u0 + v;
            bool valid = (u < dn);
            float w = hb2f(ed[v] & 0x7FFFu);
            float as_ = __uint_as_float((unsigned)__builtin_amdgcn_ds_bpermute(asl_b, (int)rr[v].w));
            float zz = fmaf(w, kh, adn) + as_;
            zz = fmaxf(zz, NEG * zz);
            float ee = __expf(zz);
            ee = valid ? ee : 0.f;
            den += ee;
            float2 y0 = __half22float2(*(const __half2*)&rr[v].x);
            float2 y1 = __half22float2(*(const __half2*)&rr[v].y);
            float2 y2 = __half22float2(*(const __half2*)&rr[v].z);
            float2 y3 = __half22float2(*(const __half2*)&rr[v].w);
            a0.x = fmaf(ee, y0.x, a0.x); a0.y = fmaf(ee, y0.y, a0.y);
            a1.x = fmaf(ee, y1.x, a1.x); a1.y = fmaf(ee, y1.y, a1.y);
            a2.x = fmaf(ee, y2.x, a2.x); a2.y = fmaf(ee, y2.y, a2.y);
            a3.x = fmaf(ee, y3.x, a3.x); a3.y = fmaf(ee, y3.y, a3.y);
        }
    }

    float rden = 0.25f / (den + 1e-16f);
    a0.x *= rden; a0.y *= rden; a1.x *= rden; a1.y *= rden;
    a2.x *= rden; a2.y *= rden; a3.x *= rden; a3.y *= rden;

    a0.x += __shfl_xor(a0.x, 4); a0.y += __shfl_xor(a0.y, 4);
    a1.x += __shfl_xor(a1.x, 4); a1.y += __shfl_xor(a1.y, 4);
    a2.x += __shfl_xor(a2.x, 4); a2.y += __shfl_xor(a2.y, 4);
    a3.x += __shfl_xor(a3.x, 4); a3.y += __shfl_xor(a3.y, 4);
    a0.x += __shfl_xor(a0.x, 8); a0.y += __shfl_xor(a0.y, 8);
    a1.x += __shfl_xor(a1.x, 8); a1.y += __shfl_xor(a1.y, 8);
    a2.x += __shfl_xor(a2.x, 8); a2.y += __shfl_xor(a2.y, 8);
    a3.x += __shfl_xor(a3.x, 8); a3.y += __shfl_xor(a3.y, 8);

    if ((k & 12) == 0) {
        int ch = k * 8;
        float v0 = fmaxf(a0.x + bias_s[ch + 0], 0.f);
        float v1 = fmaxf(a0.y + bias_s[ch + 1], 0.f);
        float v2 = fmaxf(a1.x + bias_s[ch + 2], 0.f);
        float v3 = fmaxf(a1.y + bias_s[ch + 3], 0.f);
        float v4 = fmaxf(a2.x + bias_s[ch + 4], 0.f);
        float v5 = fmaxf(a2.y + bias_s[ch + 5], 0.f);
        float v6 = fmaxf(a3.x + bias_s[ch + 6], 0.f);
        float v7 = fmaxf(a3.y + bias_s[ch + 7], 0.f);
        float* p = tb + nl * 32 + ch;
        *(float4*)p       = make_float4(v0, v1, v2, v3);
        *(float4*)(p + 4) = make_float4(v4, v5, v6, v7);
    }
    __syncthreads();

    for (int lay = 0; lay < 3; ++lay) {
        float y[2];
#pragma unroll
        for (int j = 0; j < 2; ++j) {
            int i = t + j * 256;
            int nd = i >> 5, c = i & 31;
            y[j] = 0.f;
            if (c < 30) {
                float acc = Bs[lay][c];
                const float* Wl = &Ws[lay][c * 30];
                const float* tr = &tb[nd * 32];
#pragma unroll
                for (int cc = 0; cc < 30; ++cc) acc = fmaf(tr[cc], Wl[cc], acc);
                y[j] = (lay < 2) ? fmaxf(acc, 0.f) : acc;
            }
        }
        __syncthreads();
#pragma unroll
        for (int j = 0; j < 2; ++j) {
            int i = t + j * 256;
            int nd = i >> 5, c = i & 31;
            if (c < 30) {
                if (lay < 2) tb[nd * 32 + c] = y[j];
                else out[(size_t)nids[nd] * 30 + c] = y[j];
            }
        }
        if (lay < 2) __syncthreads();
    }
}

extern "C" void kernel_launch(void* const* d_in, const int* in_sizes, int n_in,
                              void* d_out, int out_size, void* d_ws, size_t ws_size,
                              hipStream_t stream) {
    const float* h        = (const float*)d_in[0];
    const int*   ei       = (const int*)d_in[1];
    const float* ew       = (const float*)d_in[2];
    const float* gamma    = (const float*)d_in[3];
    const float* beta     = (const float*)d_in[4];
    const float* W        = (const float*)d_in[5];
    const float* att_src  = (const float*)d_in[6];
    const float* att_dst  = (const float*)d_in[7];
    const float* att_edge = (const float*)d_in[8];
    const float* Wedge    = (const float*)d_in[9];
    const float* bias     = (const float*)d_in[10];
    const float* fc1w     = (const float*)d_in[11];
    const float* fc1b     = (const float*)d_in[12];
    const float* fc2w     = (const float*)d_in[13];
    const float* fc2b     = (const float*)d_in[14];
    const float* fc3w     = (const float*)d_in[15];
    const float* fc3b     = (const float*)d_in[16];

    float*        ws     = (float*)d_ws;
    unsigned int* xh     = (unsigned int*)(ws + OFF_XH);
    float*        adstb  = ws + OFF_ADST;
    float*        par    = ws + OFF_PAR;
    int*          deg    = (int*)(ws + OFF_DEG);
    unsigned int* bcnt_g = (unsigned int*)(ws + OFF_BCNTG);
    unsigned int* adj    = (unsigned int*)(ws + OFF_ADJ);
    uint2*        gbuf   = (uint2*)(ws + OFF_GBUF);
    int*          perm   = (int*)(ws + OFF_PERM);
    float*        statp  = ws + OFF_STATP;
    float*        ewp    = ws + OFF_EWP;
    float*        out    = (float*)d_out;

    k_bin<<<BIN_BLOCKS + STATS_BLOCKS, 512, 0, stream>>>(ei, ew, h, bcnt_g, gbuf,
                                                         statp, ewp);
    k_bx<<<2 * NBUCK + X_BLOCKS, 256, 0, stream>>>(bcnt_g, gbuf, adj, deg, perm, h, W,
                                                   Wedge, att_edge, att_src, att_dst,
                                                   gamma, beta, statp, ewp, par, xh, adstb);
    k_node<<<NODE_BLOCKS, 256, 0, stream>>>((const uint4*)xh, adstb, par, deg, adj, perm,
                                            bias, fc1w, fc1b, fc2w, fc2b, fc3w, fc3b, out);
}

// Round 21
// 161.506 us; speedup vs baseline: 1.1783x; 1.0097x over previous
//
#include <hip/hip_runtime.h>
#include <hip/hip_fp16.h>

#define N_NODES 100000
#define N_EDGES 1600000
#define D_IN 30
#define H_HEADS 4
#define C_OUT 30
#define EPSV 1e-5f
#define NEG 0.2f
#define MAXDEG 48
#define NPB 64
#define NBUCK 256
#define BUCK_NODES 391        // 256*391 = 100,096 >= N
#define SLICE_CAP 48          // per-(block,bucket) slice; Poisson(16)+8sigma
#define EPB 4096
#define BIN_BLOCKS ((N_EDGES + EPB - 1) / EPB)   // 391 (512-thread blocks)
#define STATS_BLOCKS 224
#define X_BLOCKS ((N_NODES + NPB - 1) / NPB)     // 1563
#define NODE_BLOCKS (N_NODES / 16)               // 6250

// ws layout (float offsets) — total ~86.6 MB (< proven 92)
#define OFF_XH    0            // N*64 u32: 4 heads x {15 fp16x2, fp32 asrc} 256B rows
#define OFF_ADST  6400000      // N*4
#define OFF_PAR   6800000      // 4096
#define OFF_DEG   6804096      // N ints (+pad)
#define OFF_BCNTG 6904320      // BIN_BLOCKS*256 u32 = 100,096
#define OFF_ADJ   7004416      // N*MAXDEG u32
#define OFF_GBUF  11804416     // NBUCK*BIN_BLOCKS*SLICE_CAP uint2 = 9,609,216
#define OFF_PERM  21413632     // N ints
#define OFF_STATP 21513632     // STATS_BLOCKS*64 (partial BN sums; no init needed)
#define OFF_EWP   21527968     // BIN_BLOCKS floats (partial ew sums; no init needed)

__device__ __forceinline__ float hb2f(unsigned int bits) {
    __half_raw r; r.x = (unsigned short)bits;
    return __half2float(*reinterpret_cast<__half*>(&r));
}

// 512-thread blocks. [0, BIN_BLOCKS): bin 4096 edges into block-PRIVATE bucket
// slices (LDS rank, zero global atomics) + per-block ew partial sum -> ewp.
// Remaining STATS_BLOCKS: BN partial sums on h -> statp (plain stores).
__global__ __launch_bounds__(512) void k_bin(const int* __restrict__ ei,
                                             const float* __restrict__ ew,
                                             const float* __restrict__ h,
                                             unsigned int* __restrict__ bcnt_g,
                                             uint2* __restrict__ gbuf,
                                             float* __restrict__ statp,
                                             float* __restrict__ ewp) {
    int t = threadIdx.x;
    if (blockIdx.x < BIN_BLOCKS) {
        __shared__ int bcnt[NBUCK];
        __shared__ float ewsum;
        if (t < NBUCK) bcnt[t] = 0;
        if (t == 0) ewsum = 0.f;
        __syncthreads();
        int blk = blockIdx.x;
        int j0 = blk * EPB + t;
        float es = 0.f;
#pragma unroll
        for (int r = 0; r < 8; ++r) {
            int j = j0 + r * 512;
            if (j < N_EDGES) {
                int s = __builtin_nontemporal_load(ei + j);
                int d = __builtin_nontemporal_load(ei + N_EDGES + j);
                float w = __builtin_nontemporal_load(ew + j);
                es += w;
                __half hv = __float2half_rn(w);
                unsigned short hb = *reinterpret_cast<unsigned short*>(&hv);
                unsigned lo = ((unsigned)s << 15) | (unsigned)(hb & 0x7FFFu);
                int b = d / BUCK_NODES;
                int rank = atomicAdd(&bcnt[b], 1);
                if (rank < SLICE_CAP)
                    gbuf[((size_t)b * BIN_BLOCKS + blk) * SLICE_CAP + rank] =
                        make_uint2(lo, (unsigned)d);
            }
        }
        for (int off = 32; off; off >>= 1) es += __shfl_down(es, off);
        if ((t & 63) == 0) atomicAdd(&ewsum, es);
        __syncthreads();
        if (t < NBUCK) bcnt_g[(size_t)blk * NBUCK + t] = (unsigned)bcnt[t];
        if (t == 0) ewp[blk] = ewsum;
        return;
    }
    __shared__ float ls[60];
    if (t < 60) ls[t] = 0.f;
    __syncthreads();
    int sb = blockIdx.x - BIN_BLOCKS;
    float s[D_IN], q[D_IN];
#pragma unroll
    for (int d = 0; d < D_IN; ++d) { s[d] = 0.f; q[d] = 0.f; }
    int idx0 = sb * 512 + t;
    int stride = STATS_BLOCKS * 512;
    for (int r = idx0; r < N_NODES; r += stride) {
        const float* row = h + r * D_IN;
#pragma unroll
        for (int d = 0; d < D_IN; ++d) { float v = row[d]; s[d] += v; q[d] += v * v; }
    }
#pragma unroll
    for (int d = 0; d < D_IN; ++d) {
        for (int off = 32; off; off >>= 1) {
            s[d] += __shfl_down(s[d], off);
            q[d] += __shfl_down(q[d], off);
        }
    }
    if ((t & 63) == 0) {
#pragma unroll
        for (int d = 0; d < D_IN; ++d) { atomicAdd(&ls[d], s[d]); atomicAdd(&ls[30 + d], q[d]); }
    }
    __syncthreads();
    if (t < 60) statp[sb * 64 + t] = ls[t];
}

// blocks [0, NBUCK): build a FULL bucket (391 nodes) — cnt in LDS (1.6KB),
// adj entries stored directly to global; every gbuf slot scanned exactly ONCE
// (the half-bucket split and its 2x scan are gone — enabled by R20's rows
// removal). Emits degree-DESCENDING perm. Remaining X_BLOCKS: fold statp/ewp,
// x rows + inline param fold.
__global__ __launch_bounds__(256) void k_bx(const unsigned int* __restrict__ bcnt_g,
                                            const uint2* __restrict__ gbuf,
                                            unsigned int* __restrict__ adj,
                                            int* __restrict__ deg,
                                            int* __restrict__ perm,
                                            const float* __restrict__ h,
                                            const float* __restrict__ W,
                                            const float* __restrict__ Wedge,
                                            const float* __restrict__ att_edge,
                                            const float* __restrict__ att_src,
                                            const float* __restrict__ att_dst,
                                            const float* __restrict__ gamma,
                                            const float* __restrict__ beta,
                                            const float* __restrict__ statp,
                                            const float* __restrict__ ewp,
                                            float* __restrict__ par,
                                            unsigned int* __restrict__ xh,
                                            float* __restrict__ adst) {
    __shared__ __align__(16) unsigned char smem[24064];
    int t = threadIdx.x;
    if (blockIdx.x < NBUCK) {
        int* cnt  = (int*)smem;                        // [391]
        int* hist = (int*)(smem + 1568);               // [49]
        int* pfx  = (int*)(smem + 1764);               // [49]
        int b = blockIdx.x;
        int lo = b * BUCK_NODES;
        int lim = N_NODES - lo; if (lim > BUCK_NODES) lim = BUCK_NODES;
        for (int i = t; i < BUCK_NODES; i += 256) cnt[i] = 0;
        if (t < 49) hist[t] = 0;
        __syncthreads();
        const uint2* brec = gbuf + (size_t)b * BIN_BLOCKS * SLICE_CAP;
        int totslots = BIN_BLOCKS * SLICE_CAP;         // 18768, each read ONCE
        for (int i = t; i < totslots; i += 256) {
            int sl = i / SLICE_CAP;
            int r = i - sl * SLICE_CAP;
            unsigned c = bcnt_g[(size_t)sl * NBUCK + b];
            if (r < (int)c) {
                uint2 rec = brec[i];
                int li = (int)rec.y - lo;              // always in [0, lim) by keying
                int p = atomicAdd(&cnt[li], 1);
                if (p < MAXDEG)
                    adj[(size_t)(lo + li) * MAXDEG + p] = rec.x;  // direct, L2-hot
            }
        }
        __syncthreads();
        for (int i = t; i < lim; i += 256) {
            int c = cnt[i]; c = (c > MAXDEG) ? MAXDEG : c;
            deg[lo + i] = c;
            atomicAdd(&hist[c], 1);
        }
        __syncthreads();
        if (t == 0) {
            int acc = 0;
            for (int kk = MAXDEG; kk >= 0; --kk) { pfx[kk] = acc; acc += hist[kk]; }
        }
        __syncthreads();
        for (int i = t; i < lim; i += 256) {
            int c = cnt[i]; c = (c > MAXDEG) ? MAXDEG : c;
            int r = atomicAdd(&pfx[c], 1);
            perm[lo + r] = lo + i;
        }
        return;
    }
    float* W2s = (float*)smem;                 // 14400B
    float* hs  = (float*)(smem + 14400);       // 7680B
    float* psd = (float*)(smem + 22080);       // 960B
    float* cq  = (float*)(smem + 23040);       // 32B
    float* b2s = (float*)(smem + 23072);       // 480B
    float* scs = (float*)(smem + 23552);       // 120B
    float* shs = (float*)(smem + 23672);       // 120B
    float* sums = (float*)(smem + 23792);      // 240B
    int bx = blockIdx.x - NBUCK;
    if (t < 60) {
        float acc = 0.f;
        for (int i = 0; i < STATS_BLOCKS; ++i) acc += statp[i * 64 + t];
        sums[t] = acc;
    }
    if (bx == 0 && t >= 192 && t < 224) {
        int lane = t - 192;
        float acc = 0.f;
        for (int j = lane; j < BIN_BLOCKS; j += 32) acc += ewp[j];
        for (int off = 16; off; off >>= 1) acc += __shfl_down(acc, off);
        if (lane == 0) par[68] = acc * (1.f / N_EDGES);
    }
    if (bx == 0 && t >= 248 && t < 252) {
        int hh = t - 248;
        float k = 0.f;
        for (int c = 0; c < 30; ++c) k = fmaf(Wedge[hh * 30 + c], att_edge[hh * 30 + c], k);
        par[64 + hh] = k;
    }
    __syncthreads();
    if (t < D_IN) {
        float mu = sums[t] * (1.f / N_NODES);
        float var = sums[30 + t] * (1.f / N_NODES) - mu * mu;
        float inv = 1.f / sqrtf(var + EPSV);
        float sc = gamma[t] * inv;
        scs[t] = sc; shs[t] = beta[t] - mu * sc;
    }
    __syncthreads();
    {
        const float4* W4 = (const float4*)W;
        for (int i = t; i < 900; i += 256) {
            float4 w4 = W4[i];
            float sc = scs[(i * 4) / 120];
            w4.x *= sc; w4.y *= sc; w4.z *= sc; w4.w *= sc;
            *(float4*)&W2s[i * 4] = w4;
        }
    }
    if (t >= 128 && t < 248) {
        int c = t - 128;
        float b = 0.f;
#pragma unroll
        for (int d = 0; d < D_IN; ++d) b = fmaf(shs[d], W[d * 120 + c], b);
        b2s[c] = b;
    }
    __syncthreads();
    int base = bx * NPB;
    int cnt2 = N_NODES - base; if (cnt2 > NPB) cnt2 = NPB;
    if (t < 240) {
        int d = t >> 3, q = t & 7, hh = q & 3;
        const float* att = (q < 4) ? att_src : att_dst;
        float sum = 0.f;
#pragma unroll
        for (int c = 0; c < 30; ++c) sum = fmaf(W2s[d * 120 + hh * 30 + c], att[hh * 30 + c], sum);
        psd[t] = sum;
    }
    if (t >= 240 && t < 248) {
        int q = t - 240, hh = q & 3;
        const float* att = (q < 4) ? att_src : att_dst;
        float sum = 0.f;
#pragma unroll
        for (int c = 0; c < 30; ++c) sum = fmaf(b2s[hh * 30 + c], att[hh * 30 + c], sum);
        cq[q] = sum;
    }
    {
        const float4* h4 = (const float4*)(h + (size_t)base * 30);
        int n4 = (cnt2 * 30) >> 2;
        for (int i = t; i < n4; i += 256) ((float4*)hs)[i] = h4[i];
    }
    __syncthreads();
    const float2* W2p = (const float2*)W2s;
    int total = cnt2 * 60;
    for (int o = t; o < total; o += 256) {
        int node = o / 60, p = o - node * 60;
        const float* hrow = hs + node * 30;
        float ax = b2s[2 * p], ay = b2s[2 * p + 1];
        const float2* Wp = W2p + p;
#pragma unroll
        for (int d = 0; d < 30; ++d) {
            float hv = hrow[d];
            float2 w = Wp[d * 60];
            ax = fmaf(hv, w.x, ax);
            ay = fmaf(hv, w.y, ay);
        }
        __half2 pk = __float22half2_rn(make_float2(ax, ay));
        int hh = p / 15, j = p - hh * 15;
        xh[(size_t)(base + node) * 64 + hh * 16 + j] = *reinterpret_cast<unsigned int*>(&pk);
    }
    for (int v = t; v < cnt2 * 8; v += 256) {
        int node = v >> 3, q = v & 7;
        const float* hrow = hs + node * 30;
        float sum = cq[q];
#pragma unroll
        for (int d = 0; d < 30; ++d) sum = fmaf(hrow[d], psd[d * 8 + q], sum);
        int n = base + node;
        if (q < 4) xh[(size_t)n * 64 + q * 16 + 15] = __float_as_uint(sum);
        else       adst[n * H_HEADS + (q - 4)] = sum;
    }
}

// R16's k_node exactly (69us proven): degree-sorted, 4-edge batched gather
// (4 dwordx4 in flight), fused bias/ReLU + 3x(30x30) MLP. VGPR 36.
__global__ __launch_bounds__(256) void k_node(const uint4* __restrict__ xh4,
                                              const float* __restrict__ adst,
                                              const float* __restrict__ par,
                                              const int* __restrict__ deg,
                                              const unsigned int* __restrict__ adj,
                                              const int* __restrict__ perm,
                                              const float* __restrict__ bias,
                                              const float* __restrict__ fc1w,
                                              const float* __restrict__ fc1b,
                                              const float* __restrict__ fc2w,
                                              const float* __restrict__ fc2b,
                                              const float* __restrict__ fc3w,
                                              const float* __restrict__ fc3b,
                                              float* __restrict__ out) {
    __shared__ float Ws[3][900];
    __shared__ float Bs[3][30];
    __shared__ float bias_s[32];
    __shared__ float tb[16 * 32];
    __shared__ int nids[16];
    int t = threadIdx.x;
    {
        const float4* s0 = (const float4*)fc1w;
        const float4* s1 = (const float4*)fc2w;
        const float4* s2 = (const float4*)fc3w;
        for (int i = t; i < 225; i += 256) {
            *(float4*)&Ws[0][i * 4] = s0[i];
            *(float4*)&Ws[1][i * 4] = s1[i];
            *(float4*)&Ws[2][i * 4] = s2[i];
        }
    }
    if (t < 30) { Bs[0][t] = fc1b[t]; Bs[1][t] = fc2b[t]; Bs[2][t] = fc3b[t]; }
    if (t < 32) bias_s[t] = (t < 30) ? bias[t] : 0.f;
    __syncthreads();

    int l = t & 63;
    int k = l & 15;
    int wv = t >> 6;
    int q = (l >> 4) & 3;
    int nl = wv * 4 + q;
    int n = perm[blockIdx.x * 16 + nl];
    if (k == 0) nids[nl] = n;
    int h = k >> 2;
    int asl_b = (((l & 48) | (k & 12) | 3) << 2);
    int pb4 = (l & 48) << 2;

    float kh = par[64 + h];
    float ew_mean = par[68];
    float adn = adst[n * H_HEADS + h];

    int dn = min(deg[n], MAXDEG);
    int dmax = dn;
    dmax = max(dmax, __shfl_xor(dmax, 16));
    dmax = max(dmax, __shfl_xor(dmax, 32));

    const unsigned int* arow = adj + (size_t)n * MAXDEG;
    unsigned int aw0 = arow[k];
    unsigned int aw1 = 0, aw2 = 0;
    if (dmax > 16) aw1 = arow[16 + k];
    if (dmax > 32) aw2 = arow[32 + k];

    uint4 rw = xh4[(unsigned)n * 16u + (unsigned)k];
    float asn = __uint_as_float((unsigned)__builtin_amdgcn_ds_bpermute(asl_b, (int)rw.w));
    float z = fmaf(ew_mean, kh, adn) + asn;
    z = fmaxf(z, NEG * z);
    float e0 = __expf(z);
    float den = e0;
    float2 x0 = __half22float2(*(const __half2*)&rw.x);
    float2 x1 = __half22float2(*(const __half2*)&rw.y);
    float2 x2 = __half22float2(*(const __half2*)&rw.z);
    float2 x3 = __half22float2(*(const __half2*)&rw.w);
    float2 a0 = make_float2(e0 * x0.x, e0 * x0.y);
    float2 a1 = make_float2(e0 * x1.x, e0 * x1.y);
    float2 a2 = make_float2(e0 * x2.x, e0 * x2.y);
    float2 a3 = make_float2(e0 * x3.x, e0 * x3.y);

    for (int u0 = 0; u0 < dmax; u0 += 4) {
        unsigned ed[4], ss[4];
        uint4 rr[4];
#pragma unroll
        for (int v = 0; v < 4; ++v) {
            int u = u0 + v;
            unsigned int aw = (u < 16) ? aw0 : ((u < 32) ? aw1 : aw2);
            ed[v] = (unsigned)__builtin_amdgcn_ds_bpermute(pb4 + ((u & 15) << 2), (int)aw);
            ss[v] = (u < dn) ? (ed[v] >> 15) : (unsigned)n;
        }
#pragma unroll
        for (int v = 0; v < 4; ++v) rr[v] = xh4[(size_t)ss[v] * 16u + (unsigned)k];
#pragma unroll
        for (int v = 0; v < 4; ++v) {
            int u = u0 + v;
            bool valid = (u < dn);
            float w = hb2f(ed[v] & 0x7FFFu);
            float as_ = __uint_as_float((unsigned)__builtin_amdgcn_ds_bpermute(asl_b, (int)rr[v].w));
            float zz = fmaf(w, kh, adn) + as_;
            zz = fmaxf(zz, NEG * zz);
            float ee = __expf(zz);
            ee = valid ? ee : 0.f;
            den += ee;
            float2 y0 = __half22float2(*(const __half2*)&rr[v].x);
            float2 y1 = __half22float2(*(const __half2*)&rr[v].y);
            float2 y2 = __half22float2(*(const __half2*)&rr[v].z);
            float2 y3 = __half22float2(*(const __half2*)&rr[v].w);
            a0.x = fmaf(ee, y0.x, a0.x); a0.y = fmaf(ee, y0.y, a0.y);
            a1.x = fmaf(ee, y1.x, a1.x); a1.y = fmaf(ee, y1.y, a1.y);
            a2.x = fmaf(ee, y2.x, a2.x); a2.y = fmaf(ee, y2.y, a2.y);
            a3.x = fmaf(ee, y3.x, a3.x); a3.y = fmaf(ee, y3.y, a3.y);
        }
    }

    float rden = 0.25f / (den + 1e-16f);
    a0.x *= rden; a0.y *= rden; a1.x *= rden; a1.y *= rden;
    a2.x *= rden; a2.y *= rden; a3.x *= rden; a3.y *= rden;

    a0.x += __shfl_xor(a0.x, 4); a0.y += __shfl_xor(a0.y, 4);
    a1.x += __shfl_xor(a1.x, 4); a1.y += __shfl_xor(a1.y, 4);
    a2.x += __shfl_xor(a2.x, 4); a2.y += __shfl_xor(a2.y, 4);
    a3.x += __shfl_xor(a3.x, 4); a3.y += __shfl_xor(a3.y, 4);
    a0.x += __shfl_xor(a0.x, 8); a0.y += __shfl_xor(a0.y, 8);
    a1.x += __shfl_xor(a1.x, 8); a1.y += __shfl_xor(a1.y, 8);
    a2.x += __shfl_xor(a2.x, 8); a2.y += __shfl_xor(a2.y, 8);
    a3.x += __shfl_xor(a3.x, 8); a3.y += __shfl_xor(a3.y, 8);

    if ((k & 12) == 0) {
        int ch = k * 8;
        float v0 = fmaxf(a0.x + bias_s[ch + 0], 0.f);
        float v1 = fmaxf(a0.y + bias_s[ch + 1], 0.f);
        float v2 = fmaxf(a1.x + bias_s[ch + 2], 0.f);
        float v3 = fmaxf(a1.y + bias_s[ch + 3], 0.f);
        float v4 = fmaxf(a2.x + bias_s[ch + 4], 0.f);
        float v5 = fmaxf(a2.y + bias_s[ch + 5], 0.f);
        float v6 = fmaxf(a3.x + bias_s[ch + 6], 0.f);
        float v7 = fmaxf(a3.y + bias_s[ch + 7], 0.f);
        float* p = tb + nl * 32 + ch;
        *(float4*)p       = make_float4(v0, v1, v2, v3);
        *(float4*)(p + 4) = make_float4(v4, v5, v6, v7);
    }
    __syncthreads();

    for (int lay = 0; lay < 3; ++lay) {
        float y[2];
#pragma unroll
        for (int j = 0; j < 2; ++j) {
            int i = t + j * 256;
            int nd = i >> 5, c = i & 31;
            y[j] = 0.f;
            if (c < 30) {
                float acc = Bs[lay][c];
                const float* Wl = &Ws[lay][c * 30];
                const float* tr = &tb[nd * 32];
#pragma unroll
                for (int cc = 0; cc < 30; ++cc) acc = fmaf(tr[cc], Wl[cc], acc);
                y[j] = (lay < 2) ? fmaxf(acc, 0.f) : acc;
            }
        }
        __syncthreads();
#pragma unroll
        for (int j = 0; j < 2; ++j) {
            int i = t + j * 256;
            int nd = i >> 5, c = i & 31;
            if (c < 30) {
                if (lay < 2) tb[nd * 32 + c] = y[j];
                else out[(size_t)nids[nd] * 30 + c] = y[j];
            }
        }
        if (lay < 2) __syncthreads();
    }
}

extern "C" void kernel_launch(void* const* d_in, const int* in_sizes, int n_in,
                              void* d_out, int out_size, void* d_ws, size_t ws_size,
                              hipStream_t stream) {
    const float* h        = (const float*)d_in[0];
    const int*   ei       = (const int*)d_in[1];
    const float* ew       = (const float*)d_in[2];
    const float* gamma    = (const float*)d_in[3];
    const float* beta     = (const float*)d_in[4];
    const float* W        = (const float*)d_in[5];
    const float* att_src  = (const float*)d_in[6];
    const float* att_dst  = (const float*)d_in[7];
    const float* att_edge = (const float*)d_in[8];
    const float* Wedge    = (const float*)d_in[9];
    const float* bias     = (const float*)d_in[10];
    const float* fc1w     = (const float*)d_in[11];
    const float* fc1b     = (const float*)d_in[12];
    const float* fc2w     = (const float*)d_in[13];
    const float* fc2b     = (const float*)d_in[14];
    const float* fc3w     = (const float*)d_in[15];
    const float* fc3b     = (const float*)d_in[16];

    float*        ws     = (float*)d_ws;
    unsigned int* xh     = (unsigned int*)(ws + OFF_XH);
    float*        adstb  = ws + OFF_ADST;
    float*        par    = ws + OFF_PAR;
    int*          deg    = (int*)(ws + OFF_DEG);
    unsigned int* bcnt_g = (unsigned int*)(ws + OFF_BCNTG);
    unsigned int* adj    = (unsigned int*)(ws + OFF_ADJ);
    uint2*        gbuf   = (uint2*)(ws + OFF_GBUF);
    int*          perm   = (int*)(ws + OFF_PERM);
    float*        statp  = ws + OFF_STATP;
    float*        ewp    = ws + OFF_EWP;
    float*        out    = (float*)d_out;

    k_bin<<<BIN_BLOCKS + STATS_BLOCKS, 512, 0, stream>>>(ei, ew, h, bcnt_g, gbuf,
                                                         statp, ewp);
    k_bx<<<NBUCK + X_BLOCKS, 256, 0, stream>>>(bcnt_g, gbuf, adj, deg, perm, h, W,
                                               Wedge, att_edge, att_src, att_dst,
                                               gamma, beta, statp, ewp, par, xh, adstb);
    k_node<<<NODE_BLOCKS, 256, 0, stream>>>((const uint4*)xh, adstb, par, deg, adj, perm,
                                            bias, fc1w, fc1b, fc2w, fc2b, fc3w, fc3b, out);
}